// Round 1
// baseline (410.962 us; speedup 1.0000x reference)
//
#include <hip/hip_runtime.h>
#include <hip/hip_bf16.h>

// Problem constants
#define B_   4
#define L_   2048
#define D_   256
#define N_   16      // D_STATE
#define ROWS (B_*L_) // 8192
#define NC   64      // number of L-chunks
#define CL   32      // chunk length (NC*CL == L_)
#define AROW 264     // padded LDS row stride (bf16 elems) for MFMA A tiles

typedef __bf16 bf16x8 __attribute__((ext_vector_type(8)));
typedef float  f32x4  __attribute__((ext_vector_type(4)));

// ---------------- kernel A: tiny precompute: A = -exp(A_log) ----------------
__global__ __launch_bounds__(256) void k_prep(const float* __restrict__ A_log,
                                              float* __restrict__ A_neg)
{
    int idx = blockIdx.x * 256 + threadIdx.x;
    if (idx < D_ * N_) A_neg[idx] = -__expf(A_log[idx]);
}

// ---------------- kernel B: LayerNorm + projections -------------------------
// one wave per row; 4 rows per block
__global__ __launch_bounds__(256) void k_lnproj(
        const float* __restrict__ x, const float* __restrict__ ln_g, const float* __restrict__ ln_b,
        const float* __restrict__ W_xproj, const float* __restrict__ W_dt,
        const float* __restrict__ b_dt, const float* __restrict__ D_param,
        float* __restrict__ xn_o, float* __restrict__ delta_o, float* __restrict__ base_o,
        float* __restrict__ Bc_o, float* __restrict__ Cc_o)
{
    __shared__ float wdt_s[D_ * 16];
    __shared__ float dbc_s[4][16];
    int tid = threadIdx.x;
    for (int i = tid; i < D_ * 16; i += 256) wdt_s[i] = W_dt[i];
    int wave = tid >> 6, lane = tid & 63;
    int row = blockIdx.x * 4 + wave;
    const float* xr = x + row * D_;
    float v[4], xnv[4];
#pragma unroll
    for (int q = 0; q < 4; q++) v[q] = xr[lane + q * 64];
    float sum = v[0] + v[1] + v[2] + v[3];
    float sq  = v[0]*v[0] + v[1]*v[1] + v[2]*v[2] + v[3]*v[3];
#pragma unroll
    for (int off = 32; off; off >>= 1) { sum += __shfl_xor(sum, off); sq += __shfl_xor(sq, off); }
    float mu = sum * (1.f / D_);
    float rstd = rsqrtf(sq * (1.f / D_) - mu * mu + 1e-5f);
#pragma unroll
    for (int q = 0; q < 4; q++) {
        int d = lane + q * 64;
        float xv = (v[q] - mu) * rstd * ln_g[d] + ln_b[d];
        xnv[q] = xv;
        xn_o[row * D_ + d]  = xv;
        base_o[row * D_ + d] = v[q] + D_param[d] * xv;   // x + D*xn (residual base)
    }
    // dbc[j] = sum_d xn[d] * W_xproj[j][d]  (j<48), d-parallel + wave reduce
    float dbc_j = 0.f;
    for (int j = 0; j < 48; j++) {
        float p = 0.f;
#pragma unroll
        for (int q = 0; q < 4; q++) p = fmaf(xnv[q], W_xproj[j * D_ + lane + q * 64], p);
#pragma unroll
        for (int off = 32; off; off >>= 1) p += __shfl_xor(p, off);
        if (lane == j) dbc_j = p;
    }
    if (lane < 16)      dbc_s[wave][lane] = dbc_j;           // delta_r
    else if (lane < 32) Bc_o[row * 16 + lane - 16] = dbc_j;  // Bc
    else if (lane < 48) Cc_o[row * 16 + lane - 32] = dbc_j;  // Cc
    __syncthreads();
#pragma unroll
    for (int q = 0; q < 4; q++) {
        int d = lane + q * 64;
        float din = b_dt[d];
#pragma unroll
        for (int r = 0; r < 16; r++) din = fmaf(dbc_s[wave][r], wdt_s[d * 16 + r], din);
        delta_o[row * D_ + d] = (din > 15.f) ? din : log1pf(__expf(din)); // softplus
    }
}

// ---------------- kernel C: per-chunk local scan -> (P, S) ------------------
__global__ __launch_bounds__(256) void k_scan_local(
        const float* __restrict__ delta, const float* __restrict__ xn, const float* __restrict__ Bc,
        const float* __restrict__ A_neg, float* __restrict__ P, float* __restrict__ S)
{
    __shared__ float bc_s[CL * 16];
    int b = blockIdx.x / NC, c = blockIdx.x % NC;
    int d = threadIdx.x;
    int rowbase = b * L_ + c * CL;
    for (int i = d; i < CL * 16; i += 256) bc_s[i] = Bc[rowbase * 16 + i];
    float ar[16], p[16], s[16];
#pragma unroll
    for (int n = 0; n < 16; n++) { ar[n] = A_neg[d * 16 + n]; p[n] = 1.f; s[n] = 0.f; }
    __syncthreads();
    for (int t = 0; t < CL; t++) {
        int row = rowbase + t;
        float dlt = delta[row * D_ + d];
        float dx  = dlt * xn[row * D_ + d];
#pragma unroll
        for (int n = 0; n < 16; n++) {
            float e = __expf(dlt * ar[n]);
            s[n] = fmaf(e, s[n], dx * bc_s[t * 16 + n]);
            p[n] *= e;
        }
    }
    int o = blockIdx.x * 4096 + d * 16;
#pragma unroll
    for (int n = 0; n < 16; n++) { P[o + n] = p[n]; S[o + n] = s[n]; }
}

// ---------------- kernel D: inter-chunk scan -> H0 per chunk ----------------
__global__ __launch_bounds__(256) void k_scan_chunks(
        const float* __restrict__ P, const float* __restrict__ S, float* __restrict__ H0)
{
    int g = blockIdx.x * 256 + threadIdx.x;  // 16384 channels
    int b = g >> 12, dn = g & 4095;
    float h = 0.f;
    for (int c = 0; c < NC; c++) {
        int idx = (b * NC + c) * 4096 + dn;
        H0[idx] = h;
        h = fmaf(P[idx], h, S[idx]);
    }
}

// ---------------- kernel E: re-scan + fused truncated-DFT (MFMA) ------------
// hf[row][i][x] = sum_d h[row][d][i] * E[d][x];  E[:,x<32]=cos, E[:,x>=32]=-sin
__global__ __launch_bounds__(256) void k_scan_fft(
        const float* __restrict__ delta, const float* __restrict__ xn, const float* __restrict__ Bc,
        const float* __restrict__ A_neg, const float* __restrict__ H0,
        __hip_bfloat16* __restrict__ hf)
{
    __shared__ __align__(16) __bf16 a_lds[64 * AROW];
    __shared__ float bc_s[CL * 16];
    int b = blockIdx.x / NC, c = blockIdx.x % NC;
    int tid = threadIdx.x;
    int d = tid, wave = tid >> 6, lane = tid & 63;
    int rowbase = b * L_ + c * CL;
    for (int i = tid; i < CL * 16; i += 256) bc_s[i] = Bc[rowbase * 16 + i];
    float ar[16], h[16];
    {
        int ho = blockIdx.x * 4096 + d * 16;
#pragma unroll
        for (int n = 0; n < 16; n++) { ar[n] = A_neg[d * 16 + n]; h[n] = H0[ho + n]; }
    }
    // B fragments: B[k=dd][n=xx], lane holds n=lane&15, k=(lane>>4)*8+j
    int xx = wave * 16 + (lane & 15);
    bf16x8 bfrag[8];
    {
        const float ang = 6.28318530717958647693f / 256.f;
#pragma unroll
        for (int ks = 0; ks < 8; ks++) {
#pragma unroll
            for (int j = 0; j < 8; j++) {
                int dd = ks * 32 + ((lane >> 4) * 8) + j;
                float val;
                if (xx < 32) val =  cosf(ang * (float)((xx * dd) & 255));
                else         val = -sinf(ang * (float)(((xx - 32) * dd) & 255));
                bfrag[ks][j] = (__bf16)val;
            }
        }
    }
    f32x4 acc[4];
#pragma unroll
    for (int mt = 0; mt < 4; mt++) { acc[mt][0]=0.f; acc[mt][1]=0.f; acc[mt][2]=0.f; acc[mt][3]=0.f; }
    __syncthreads();
    for (int g4 = 0; g4 < CL / 4; g4++) {
        // scan phase: 4 timesteps, write h as bf16 A-tile rows (m = tl*16+i, k = d)
#pragma unroll
        for (int tl = 0; tl < 4; tl++) {
            int t = g4 * 4 + tl;
            int row = rowbase + t;
            float dlt = delta[row * D_ + d];
            float dx  = dlt * xn[row * D_ + d];
#pragma unroll
            for (int n = 0; n < 16; n++) {
                float e = __expf(dlt * ar[n]);
                h[n] = fmaf(e, h[n], dx * bc_s[t * 16 + n]);
                a_lds[(tl * 16 + n) * AROW + d] = (__bf16)h[n];
            }
        }
        __syncthreads();
        // MFMA phase: wave w owns N-tile (x = w*16..w*16+15); loop M-tiles (=timestep) and K
#pragma unroll
        for (int ks = 0; ks < 8; ks++) {
#pragma unroll
            for (int mt = 0; mt < 4; mt++) {
                bf16x8 af = *reinterpret_cast<const bf16x8*>(
                    &a_lds[(mt * 16 + (lane & 15)) * AROW + ks * 32 + ((lane >> 4) * 8)]);
                acc[mt] = __builtin_amdgcn_mfma_f32_16x16x32_bf16(af, bfrag[ks], acc[mt], 0, 0, 0);
            }
        }
        __syncthreads();
        // store hf (C/D layout: col=lane&15, row=(lane>>4)*4+reg) and reset acc
#pragma unroll
        for (int mt = 0; mt < 4; mt++) {
            int row = rowbase + g4 * 4 + mt;
#pragma unroll
            for (int q = 0; q < 4; q++) {
                int i = (lane >> 4) * 4 + q;
                hf[row * 1024 + i * 64 + xx] = __float2bfloat16(acc[mt][q]);
                acc[mt][q] = 0.f;
            }
        }
    }
}

// ---------------- kernel F: mode mixing + inverse transform + epilogue ------
__global__ __launch_bounds__(256) void k_mix_out(
        const __hip_bfloat16* __restrict__ hf, const float* __restrict__ Cc,
        const float* __restrict__ w_re, const float* __restrict__ w_im,
        const float* __restrict__ base, float* __restrict__ out)
{
    __shared__ float hf_s[8][1024];
    __shared__ float g_s[8][32][2];
    __shared__ float cc_s[8][16];
    int tid = threadIdx.x;
    int row0 = blockIdx.x * 8;
    for (int i = tid; i < 8 * 1024; i += 256) {
        int r = i >> 10, k = i & 1023;
        hf_s[r][k] = __bfloat162float(hf[(row0 + r) * 1024 + k]);
    }
    if (tid < 128) cc_s[tid >> 4][tid & 15] = Cc[(row0 + (tid >> 4)) * 16 + (tid & 15)];
    __syncthreads();
    {   // g[r][x] = sum_o Cc[o] * sum_i hf[i,x]*w[i,o,x]   (complex)
        int r = tid >> 5, xm = tid & 31;
        float gre = 0.f, gim = 0.f;
        for (int o = 0; o < 16; o++) {
            float ofr = 0.f, ofi = 0.f;
#pragma unroll 4
            for (int i = 0; i < 16; i++) {
                float wre = w_re[(i * 16 + o) * 32 + xm];
                float wim = w_im[(i * 16 + o) * 32 + xm];
                float hr = hf_s[r][i * 64 + xm];
                float hi = hf_s[r][i * 64 + 32 + xm];
                ofr += hr * wre - hi * wim;
                ofi += hr * wim + hi * wre;
            }
            gre = fmaf(cc_s[r][o], ofr, gre);
            gim = fmaf(cc_s[r][o], ofi, gim);
        }
        g_s[r][xm][0] = gre; g_s[r][xm][1] = gim;
    }
    __syncthreads();
    // inverse: y[d] = (g0.re + 2*sum_{x=1..31} (gre*cos - gim*sin)) / 256
    int d = tid;
    float acc[8];
#pragma unroll
    for (int r = 0; r < 8; r++) acc[r] = 0.f;
    const float ang = 6.28318530717958647693f / 256.f;
    for (int xm = 1; xm < 32; xm++) {
        float sph, cph;
        sincosf(ang * (float)((xm * d) & 255), &sph, &cph);
#pragma unroll
        for (int r = 0; r < 8; r++)
            acc[r] += g_s[r][xm][0] * cph - g_s[r][xm][1] * sph;
    }
#pragma unroll
    for (int r = 0; r < 8; r++) {
        int row = row0 + r;
        out[row * D_ + d] = base[row * D_ + d] + (g_s[r][0][0] + 2.f * acc[r]) * (1.f / 256.f);
    }
}

// ---------------- launch -----------------------------------------------------
extern "C" void kernel_launch(void* const* d_in, const int* in_sizes, int n_in,
                              void* d_out, int out_size, void* d_ws, size_t ws_size,
                              hipStream_t stream)
{
    const float* x       = (const float*)d_in[0];
    const float* ln_g    = (const float*)d_in[1];
    const float* ln_b    = (const float*)d_in[2];
    const float* W_xproj = (const float*)d_in[3];
    const float* W_dt    = (const float*)d_in[4];
    const float* b_dt    = (const float*)d_in[5];
    const float* A_log   = (const float*)d_in[6];
    const float* D_param = (const float*)d_in[7];
    const float* w_re    = (const float*)d_in[8];
    const float* w_im    = (const float*)d_in[9];

    float* ws    = (float*)d_ws;                  // ws usage: ~55.6 MB total
    float* A_neg = ws;                            // 4096
    float* xn    = ws + 16384;                    // 2097152
    float* delta = xn + 2097152;                  // 2097152
    float* base  = delta + 2097152;               // 2097152
    float* Bc    = base + 2097152;                // 131072
    float* Cc    = Bc + 131072;                   // 131072
    float* P     = Cc + 131072;                   // 1048576
    float* S     = P + 1048576;                   // 1048576
    float* H0    = S + 1048576;                   // 1048576
    __hip_bfloat16* hf = (__hip_bfloat16*)(H0 + 1048576);  // 8388608 bf16
    float* out = (float*)d_out;

    hipLaunchKernelGGL(k_prep,        dim3(16),   dim3(256), 0, stream, A_log, A_neg);
    hipLaunchKernelGGL(k_lnproj,      dim3(ROWS/4), dim3(256), 0, stream,
                       x, ln_g, ln_b, W_xproj, W_dt, b_dt, D_param, xn, delta, base, Bc, Cc);
    hipLaunchKernelGGL(k_scan_local,  dim3(B_*NC), dim3(256), 0, stream, delta, xn, Bc, A_neg, P, S);
    hipLaunchKernelGGL(k_scan_chunks, dim3(64),   dim3(256), 0, stream, P, S, H0);
    hipLaunchKernelGGL(k_scan_fft,    dim3(B_*NC), dim3(256), 0, stream, delta, xn, Bc, A_neg, H0, hf);
    hipLaunchKernelGGL(k_mix_out,     dim3(ROWS/8), dim3(256), 0, stream, hf, Cc, w_re, w_im, base, out);
}

// Round 2
// 205.321 us; speedup vs baseline: 2.0016x; 2.0016x over previous
//
#include <hip/hip_runtime.h>
#include <hip/hip_bf16.h>

// Problem constants
#define B_   4
#define L_   2048
#define D_   256
#define N_   16       // D_STATE
#define ROWS (B_*L_)  // 8192
#define NC   128      // number of L-chunks
#define CL   16       // chunk length (NC*CL == L_)
#define ANG  0.02454369260617025967f   // 2*pi/256

typedef __bf16 bf16x8 __attribute__((ext_vector_type(8)));
typedef float  f32x4  __attribute__((ext_vector_type(4)));

// ---------------- kernel A: tiny precompute: A = -exp(A_log) ----------------
__global__ __launch_bounds__(256) void k_prep(const float* __restrict__ A_log,
                                              float* __restrict__ A_neg)
{
    int idx = blockIdx.x * 256 + threadIdx.x;
    if (idx < D_ * N_) A_neg[idx] = -__expf(A_log[idx]);
}

// ---------------- kernel B: LayerNorm + projections -------------------------
// one wave per row; 4 rows per block
__global__ __launch_bounds__(256) void k_lnproj(
        const float* __restrict__ x, const float* __restrict__ ln_g, const float* __restrict__ ln_b,
        const float* __restrict__ W_xproj, const float* __restrict__ W_dt,
        const float* __restrict__ b_dt, const float* __restrict__ D_param,
        float* __restrict__ xn_o, float* __restrict__ delta_o, float* __restrict__ base_o,
        float* __restrict__ Bc_o, float* __restrict__ Cc_o)
{
    __shared__ float wdt_s[D_ * 16];
    __shared__ float dbc_s[4][16];
    int tid = threadIdx.x;
    for (int i = tid; i < D_ * 16; i += 256) wdt_s[i] = W_dt[i];
    int wave = tid >> 6, lane = tid & 63;
    int row = blockIdx.x * 4 + wave;
    const float* xr = x + row * D_;
    float v[4], xnv[4];
#pragma unroll
    for (int q = 0; q < 4; q++) v[q] = xr[lane + q * 64];
    float sum = v[0] + v[1] + v[2] + v[3];
    float sq  = v[0]*v[0] + v[1]*v[1] + v[2]*v[2] + v[3]*v[3];
#pragma unroll
    for (int off = 32; off; off >>= 1) { sum += __shfl_xor(sum, off); sq += __shfl_xor(sq, off); }
    float mu = sum * (1.f / D_);
    float rstd = rsqrtf(sq * (1.f / D_) - mu * mu + 1e-5f);
#pragma unroll
    for (int q = 0; q < 4; q++) {
        int d = lane + q * 64;
        float xv = (v[q] - mu) * rstd * ln_g[d] + ln_b[d];
        xnv[q] = xv;
        xn_o[row * D_ + d]  = xv;
        base_o[row * D_ + d] = v[q] + D_param[d] * xv;   // x + D*xn (residual base)
    }
    float dbc_j = 0.f;
    for (int j = 0; j < 48; j++) {
        float p = 0.f;
#pragma unroll
        for (int q = 0; q < 4; q++) p = fmaf(xnv[q], W_xproj[j * D_ + lane + q * 64], p);
#pragma unroll
        for (int off = 32; off; off >>= 1) p += __shfl_xor(p, off);
        if (lane == j) dbc_j = p;
    }
    if (lane < 16)      dbc_s[wave][lane] = dbc_j;           // delta_r
    else if (lane < 32) Bc_o[row * 16 + lane - 16] = dbc_j;  // Bc
    else if (lane < 48) Cc_o[row * 16 + lane - 32] = dbc_j;  // Cc
    __syncthreads();
#pragma unroll
    for (int q = 0; q < 4; q++) {
        int d = lane + q * 64;
        float din = b_dt[d];
#pragma unroll
        for (int r = 0; r < 16; r++) din = fmaf(dbc_s[wave][r], wdt_s[d * 16 + r], din);
        delta_o[row * D_ + d] = (din > 15.f) ? din : log1pf(__expf(din)); // softplus
    }
}

// ---------------- kernel C: per-chunk local scan -> (P, S) ------------------
__global__ __launch_bounds__(256) void k_scan_local(
        const float* __restrict__ delta, const float* __restrict__ xn, const float* __restrict__ Bc,
        const float* __restrict__ A_neg, float* __restrict__ P, float* __restrict__ S)
{
    __shared__ __align__(16) float bc_s[CL * 16];
    int blk = blockIdx.x;            // = b*NC + c
    int d = threadIdx.x;
    int rowbase = blk * CL;          // global row (b-major chunk order)
    bc_s[d] = Bc[rowbase * 16 + d];  // 256 floats = CL*16
    float ar[16], p[16], s[16];
#pragma unroll
    for (int q = 0; q < 4; q++) {
        f32x4 a4 = *reinterpret_cast<const f32x4*>(&A_neg[d * 16 + q * 4]);
#pragma unroll
        for (int k = 0; k < 4; k++) { ar[q*4+k] = a4[k]; p[q*4+k] = 1.f; s[q*4+k] = 0.f; }
    }
    __syncthreads();
    for (int t = 0; t < CL; t++) {
        int row = rowbase + t;
        float dlt = delta[row * D_ + d];
        float dx  = dlt * xn[row * D_ + d];
        f32x4 bcv[4];
#pragma unroll
        for (int q = 0; q < 4; q++) bcv[q] = *reinterpret_cast<const f32x4*>(&bc_s[t * 16 + q * 4]);
#pragma unroll
        for (int n = 0; n < 16; n++) {
            float e = __expf(dlt * ar[n]);
            s[n] = fmaf(e, s[n], dx * bcv[n >> 2][n & 3]);
            p[n] *= e;
        }
    }
    int o = blk * 4096 + d * 16;
#pragma unroll
    for (int q = 0; q < 4; q++) {
        f32x4 pv, sv;
#pragma unroll
        for (int k = 0; k < 4; k++) { pv[k] = p[q*4+k]; sv[k] = s[q*4+k]; }
        *reinterpret_cast<f32x4*>(&P[o + q * 4]) = pv;
        *reinterpret_cast<f32x4*>(&S[o + q * 4]) = sv;
    }
}

// ---------------- kernel D: inter-chunk scan; H0 overwrites S in place ------
__global__ __launch_bounds__(64) void k_scan_chunks(
        const float* __restrict__ P, float* __restrict__ S_H0)
{
    int b = blockIdx.x >> 6, seg = blockIdx.x & 63;
    int dn = seg * 64 + threadIdx.x;
    float h = 0.f;
    for (int c = 0; c < NC; c++) {
        int idx = (b * NC + c) * 4096 + dn;
        float pv = P[idx];
        float sv = S_H0[idx];
        S_H0[idx] = h;             // H0 for this chunk (read S first!)
        h = fmaf(pv, h, sv);
    }
}

// ---------------- kernel E: re-scan, store hs bf16 (swizzled cols) ----------
// hs layout (per batch slice b): hs[m][d'] with m = (c*CL+t)*16 + n,
// d' = d ^ ((n&7)<<3)   (pre-swizzle so consumer's ds_read_b128 is conflict-free)
__global__ __launch_bounds__(256) void k_rescan(
        const float* __restrict__ delta, const float* __restrict__ xn, const float* __restrict__ Bc,
        const float* __restrict__ A_neg, const float* __restrict__ H0,
        __hip_bfloat16* __restrict__ hs, int b)
{
    __shared__ __align__(16) float bc_s[CL * 16];
    int c = blockIdx.x;
    int d = threadIdx.x;
    int growbase = b * L_ + c * CL;
    bc_s[d] = Bc[growbase * 16 + d];
    float ar[16], h[16];
    int ho = (b * NC + c) * 4096 + d * 16;
#pragma unroll
    for (int q = 0; q < 4; q++) {
        f32x4 a4 = *reinterpret_cast<const f32x4*>(&A_neg[d * 16 + q * 4]);
        f32x4 h4 = *reinterpret_cast<const f32x4*>(&H0[ho + q * 4]);
#pragma unroll
        for (int k = 0; k < 4; k++) { ar[q*4+k] = a4[k]; h[q*4+k] = h4[k]; }
    }
    __syncthreads();
    for (int t = 0; t < CL; t++) {
        int grow = growbase + t;
        float dlt = delta[grow * D_ + d];
        float dx  = dlt * xn[grow * D_ + d];
        f32x4 bcv[4];
#pragma unroll
        for (int q = 0; q < 4; q++) bcv[q] = *reinterpret_cast<const f32x4*>(&bc_s[t * 16 + q * 4]);
        int mbase = (c * CL + t) * 16;
#pragma unroll
        for (int n = 0; n < 16; n++) {
            float e = __expf(dlt * ar[n]);
            h[n] = fmaf(e, h[n], dx * bcv[n >> 2][n & 3]);
            int dsw = d ^ ((n & 7) << 3);
            hs[(mbase + n) * D_ + dsw] = __float2bfloat16(h[n]);
        }
    }
}

// ---------------- kernel F: DFT (MFMA) + mode-mix + inverse + epilogue ------
// block = 4 consecutive rows of batch b (64 m-rows); no hf round-trip.
__global__ __launch_bounds__(256) void k_dftmix(
        const __hip_bfloat16* __restrict__ hs, const float* __restrict__ Cc,
        const float* __restrict__ w_re, const float* __restrict__ w_im,
        const float* __restrict__ base, float* __restrict__ out, int b)
{
    __shared__ __align__(16) char smem[32768];
    float* hf_s  = (float*)smem;              // [4][1024] f32 (reuses A-tile space)
    float* gpart = (float*)(smem + 16384);    // [4 q][32 xm][4 r][2]
    float* g_s   = (float*)(smem + 20480);    // [4 r][32 xm][2]
    float* cc_s  = (float*)(smem + 21504);    // [4 r][16 o]
    int tid = threadIdx.x, wave = tid >> 6, lane = tid & 63;
    int R0 = blockIdx.x * 4;                  // local row within batch b
    int M0 = R0 * 16;                         // first m-row of A-tile

    // --- B fragments: E[d][x] (x<32: cos, x>=32: -sin), hw trig ---
    int xx = wave * 16 + (lane & 15);
    bf16x8 bfrag[8];
#pragma unroll
    for (int ks = 0; ks < 8; ks++) {
#pragma unroll
        for (int j = 0; j < 8; j++) {
            int dd = ks * 32 + ((lane >> 4) * 8) + j;
            float val;
            if (xx < 32) val =  __cosf(ANG * (float)((xx * dd) & 255));
            else         val = -__sinf(ANG * (float)(((xx - 32) * dd) & 255));
            bfrag[ks][j] = (__bf16)val;
        }
    }
    // --- stage A-tile (64 rows x 512B, already swizzled by producer) ---
    {
        const uint4* gp = (const uint4*)(hs + M0 * D_);
#pragma unroll
        for (int p = 0; p < 8; p++) {
            uint4 v = gp[p * 256 + tid];
            *reinterpret_cast<uint4*>(smem + p * 4096 + tid * 16) = v;
        }
    }
    __syncthreads();
    // --- MFMA: hf[m][x] = sum_d A[m][d] * E[d][x] ---
    f32x4 acc[4];
#pragma unroll
    for (int mt = 0; mt < 4; mt++) { acc[mt][0]=0.f; acc[mt][1]=0.f; acc[mt][2]=0.f; acc[mt][3]=0.f; }
#pragma unroll
    for (int ks = 0; ks < 8; ks++) {
#pragma unroll
        for (int mt = 0; mt < 4; mt++) {
            int mrow = mt * 16 + (lane & 15);
            int byte = mrow * 512 + ((ks * 32 + ((lane >> 4) * 8)) << 1);
            byte ^= (mrow & 7) << 4;          // undo producer swizzle
            bf16x8 af = *reinterpret_cast<const bf16x8*>(smem + byte);
            acc[mt] = __builtin_amdgcn_mfma_f32_16x16x32_bf16(af, bfrag[ks], acc[mt], 0, 0, 0);
        }
    }
    __syncthreads();   // all frag reads done; reuse smem for hf_s
    // C/D layout: col = lane&15 (x-offset), row = (lane>>4)*4+q (i = state idx)
#pragma unroll
    for (int mt = 0; mt < 4; mt++) {
#pragma unroll
        for (int q = 0; q < 4; q++) {
            int i = (lane >> 4) * 4 + q;
            hf_s[mt * 1024 + i * 64 + xx] = acc[mt][q];
        }
    }
    if (tid < 64) {
        int r = tid >> 4, o = tid & 15;
        cc_s[r * 16 + o] = Cc[(b * L_ + R0 + r) * 16 + o];
    }
    __syncthreads();
    // --- mix: g[r][x] = sum_o Cc[r][o] * sum_i hf[r][i][x]*w[i][o][x] ---
    if (tid < 128) {
        int xm = tid & 31, q = tid >> 5;      // q = o-quarter
        float gre[4] = {0,0,0,0}, gim[4] = {0,0,0,0};
        for (int i = 0; i < 16; i++) {
            float hr[4], hi[4];
#pragma unroll
            for (int r = 0; r < 4; r++) {
                hr[r] = hf_s[r * 1024 + i * 64 + xm];
                hi[r] = hf_s[r * 1024 + i * 64 + 32 + xm];
            }
#pragma unroll
            for (int oo = 0; oo < 4; oo++) {
                int o = q * 4 + oo;
                float wre = w_re[(i * 16 + o) * 32 + xm];
                float wim = w_im[(i * 16 + o) * 32 + xm];
#pragma unroll
                for (int r = 0; r < 4; r++) {
                    float tre = hr[r] * wre - hi[r] * wim;
                    float tim = hr[r] * wim + hi[r] * wre;
                    float cc = cc_s[r * 16 + o];
                    gre[r] = fmaf(cc, tre, gre[r]);
                    gim[r] = fmaf(cc, tim, gim[r]);
                }
            }
        }
#pragma unroll
        for (int r = 0; r < 4; r++) {
            gpart[((q * 32 + xm) * 4 + r) * 2 + 0] = gre[r];
            gpart[((q * 32 + xm) * 4 + r) * 2 + 1] = gim[r];
        }
    }
    __syncthreads();
    if (tid < 128) {
        int r = tid >> 5, xm = tid & 31;
        float gre = 0.f, gim = 0.f;
#pragma unroll
        for (int q = 0; q < 4; q++) {
            gre += gpart[((q * 32 + xm) * 4 + r) * 2 + 0];
            gim += gpart[((q * 32 + xm) * 4 + r) * 2 + 1];
        }
        g_s[(r * 32 + xm) * 2 + 0] = gre;
        g_s[(r * 32 + xm) * 2 + 1] = gim;
    }
    __syncthreads();
    // --- inverse (32 modes) + epilogue ---
    int d = tid;
    float acc4[4] = {0,0,0,0};
    for (int xm = 1; xm < 32; xm++) {
        float a = ANG * (float)((xm * d) & 255);
        float cph = __cosf(a), sph = __sinf(a);
#pragma unroll
        for (int r = 0; r < 4; r++)
            acc4[r] += g_s[(r * 32 + xm) * 2 + 0] * cph - g_s[(r * 32 + xm) * 2 + 1] * sph;
    }
#pragma unroll
    for (int r = 0; r < 4; r++) {
        int grow = b * L_ + R0 + r;
        out[grow * D_ + d] = base[grow * D_ + d]
                           + (g_s[(r * 32) * 2] + 2.f * acc4[r]) * (1.f / 256.f);
    }
}

// ---------------- launch -----------------------------------------------------
extern "C" void kernel_launch(void* const* d_in, const int* in_sizes, int n_in,
                              void* d_out, int out_size, void* d_ws, size_t ws_size,
                              hipStream_t stream)
{
    const float* x       = (const float*)d_in[0];
    const float* ln_g    = (const float*)d_in[1];
    const float* ln_b    = (const float*)d_in[2];
    const float* W_xproj = (const float*)d_in[3];
    const float* W_dt    = (const float*)d_in[4];
    const float* b_dt    = (const float*)d_in[5];
    const float* A_log   = (const float*)d_in[6];
    const float* D_param = (const float*)d_in[7];
    const float* w_re    = (const float*)d_in[8];
    const float* w_im    = (const float*)d_in[9];

    // workspace layout (floats) — total 51.4 MB
    float* ws    = (float*)d_ws;
    float* A_neg = ws;                         // 4096
    float* xn    = A_neg + 4096;               // 2M
    float* delta = xn + 2097152;               // 2M
    float* base  = delta + 2097152;            // 2M
    float* Bc    = base + 2097152;             // 131072
    float* Cc    = Bc + 131072;                // 131072
    float* S_H0  = Cc + 131072;                // 2M (S, then H0 in place)
    float* P     = S_H0 + 2097152;             // 2M (dies after scan_chunks)
    __hip_bfloat16* hs = (__hip_bfloat16*)P;   // 8.4M bf16 slice, overlays P + 2M extra
    float* out = (float*)d_out;

    hipLaunchKernelGGL(k_prep,        dim3(16),      dim3(256), 0, stream, A_log, A_neg);
    hipLaunchKernelGGL(k_lnproj,      dim3(ROWS/4),  dim3(256), 0, stream,
                       x, ln_g, ln_b, W_xproj, W_dt, b_dt, D_param, xn, delta, base, Bc, Cc);
    hipLaunchKernelGGL(k_scan_local,  dim3(B_*NC),   dim3(256), 0, stream, delta, xn, Bc, A_neg, P, S_H0);
    hipLaunchKernelGGL(k_scan_chunks, dim3(256),     dim3(64),  0, stream, P, S_H0);
    for (int b = 0; b < B_; b++) {
        hipLaunchKernelGGL(k_rescan,  dim3(NC),      dim3(256), 0, stream,
                           delta, xn, Bc, A_neg, S_H0, hs, b);
        hipLaunchKernelGGL(k_dftmix,  dim3(L_/4),    dim3(256), 0, stream,
                           hs, Cc, w_re, w_im, base, out, b);
    }
}

// Round 3
// 147.756 us; speedup vs baseline: 2.7814x; 1.3896x over previous
//
#include <hip/hip_runtime.h>
#include <hip/hip_bf16.h>

// Problem constants
#define B_   4
#define L_   2048
#define D_   256
#define N_   16       // D_STATE
#define NC   128      // number of L-chunks
#define CL   16       // chunk length (NC*CL == L_)
#define ANG  0.02454369260617025967f   // 2*pi/256

typedef __bf16 bf16x8 __attribute__((ext_vector_type(8)));
typedef float  f32x4  __attribute__((ext_vector_type(4)));

// ---------------- kernel A: tiny precompute: A = -exp(A_log) ----------------
__global__ __launch_bounds__(256) void k_prep(const float* __restrict__ A_log,
                                              float* __restrict__ A_neg)
{
    int idx = blockIdx.x * 256 + threadIdx.x;
    if (idx < D_ * N_) A_neg[idx] = -__expf(A_log[idx]);
}

// ---------------- kernel B: LN + proj + delta + local scan (per 16-row chunk)
__global__ __launch_bounds__(256) void k_lnscan(
        const float* __restrict__ x, const float* __restrict__ ln_g, const float* __restrict__ ln_b,
        const float* __restrict__ W_xproj, const float* __restrict__ W_dt,
        const float* __restrict__ b_dt, const float* __restrict__ D_param,
        const float* __restrict__ A_neg,
        float* __restrict__ xn_o, float* __restrict__ delta_o, float* __restrict__ base_o,
        float* __restrict__ Bc_o, float* __restrict__ Cc_o,
        float* __restrict__ P, float* __restrict__ S)
{
    __shared__ __align__(16) float xn_s[16 * 264];   // +8 pad: 4-way max on b128
    __shared__ float dbc_s[16 * 52];
    int tid = threadIdx.x, wave = tid >> 6, lane = tid & 63;
    int blk = blockIdx.x;
    int grow0 = blk * CL;

    // --- Phase A: LayerNorm, 4 rows per wave ---
#pragma unroll
    for (int rr = 0; rr < 4; rr++) {
        int r = wave * 4 + rr;
        const float* xr = x + (size_t)(grow0 + r) * D_;
        float v[4];
#pragma unroll
        for (int q = 0; q < 4; q++) v[q] = xr[lane + q * 64];
        float sum = v[0] + v[1] + v[2] + v[3];
        float sq  = v[0]*v[0] + v[1]*v[1] + v[2]*v[2] + v[3]*v[3];
#pragma unroll
        for (int off = 32; off; off >>= 1) { sum += __shfl_xor(sum, off); sq += __shfl_xor(sq, off); }
        float mu = sum * (1.f / D_);
        float rstd = rsqrtf(sq * (1.f / D_) - mu * mu + 1e-5f);
#pragma unroll
        for (int q = 0; q < 4; q++) {
            int d = lane + q * 64;
            float xv = (v[q] - mu) * rstd * ln_g[d] + ln_b[d];
            xn_s[r * 264 + d] = xv;
            xn_o[(size_t)(grow0 + r) * D_ + d] = xv;
            base_o[(size_t)(grow0 + r) * D_ + d] = v[q] + D_param[d] * xv;
        }
    }
    __syncthreads();

    // --- Phase B: dbc[row][j] = xn[row] . W_xproj[j]  (thread = (row, 3 j's)) ---
    {
        int row = tid & 15, jg = tid >> 4;
        const f32x4* xs4 = (const f32x4*)&xn_s[row * 264];
        const f32x4* w0 = (const f32x4*)&W_xproj[(size_t)(jg * 3 + 0) * D_];
        const f32x4* w1 = (const f32x4*)&W_xproj[(size_t)(jg * 3 + 1) * D_];
        const f32x4* w2 = (const f32x4*)&W_xproj[(size_t)(jg * 3 + 2) * D_];
        float a0 = 0.f, a1 = 0.f, a2 = 0.f;
        for (int e4 = 0; e4 < 64; e4++) {
            f32x4 xv = xs4[e4];
            f32x4 wa = w0[e4], wb = w1[e4], wc = w2[e4];
#pragma unroll
            for (int k = 0; k < 4; k++) {
                a0 = fmaf(xv[k], wa[k], a0);
                a1 = fmaf(xv[k], wb[k], a1);
                a2 = fmaf(xv[k], wc[k], a2);
            }
        }
        float av[3] = {a0, a1, a2};
        int grow = grow0 + row;
#pragma unroll
        for (int jj = 0; jj < 3; jj++) {
            int j = jg * 3 + jj;
            dbc_s[row * 52 + j] = av[jj];
            if (j >= 32)      Cc_o[(size_t)grow * 16 + j - 32] = av[jj];
            else if (j >= 16) Bc_o[(size_t)grow * 16 + j - 16] = av[jj];
        }
    }
    __syncthreads();

    // --- Phase C: delta[row][d] = softplus(dbc[row][:16] . W_dt[d] + b_dt[d]) ---
    int d = tid;
    float wdt[16];
#pragma unroll
    for (int q = 0; q < 4; q++) {
        f32x4 w4 = *(const f32x4*)&W_dt[d * 16 + q * 4];
#pragma unroll
        for (int k = 0; k < 4; k++) wdt[q * 4 + k] = w4[k];
    }
    float bd = b_dt[d];
    float dlt_r[16];
#pragma unroll
    for (int r = 0; r < 16; r++) {
        float din = bd;
#pragma unroll
        for (int k = 0; k < 16; k++) din = fmaf(dbc_s[r * 52 + k], wdt[k], din);
        din = (din > 15.f) ? din : log1pf(__expf(din));
        dlt_r[r] = din;
        delta_o[(size_t)(grow0 + r) * D_ + d] = din;
    }

    // --- Phase D: local scan over 16 timesteps ---
    float ar[16], p[16], s[16];
#pragma unroll
    for (int q = 0; q < 4; q++) {
        f32x4 a4 = *(const f32x4*)&A_neg[d * 16 + q * 4];
#pragma unroll
        for (int k = 0; k < 4; k++) { ar[q*4+k] = a4[k]; p[q*4+k] = 1.f; s[q*4+k] = 0.f; }
    }
#pragma unroll
    for (int t = 0; t < CL; t++) {
        float dlt = dlt_r[t];
        float dx  = dlt * xn_s[t * 264 + d];
#pragma unroll
        for (int n = 0; n < 16; n++) {
            float e = __expf(dlt * ar[n]);
            s[n] = fmaf(e, s[n], dx * dbc_s[t * 52 + 16 + n]);
            p[n] *= e;
        }
    }
    size_t o = (size_t)blk * 4096 + d * 16;
#pragma unroll
    for (int q = 0; q < 4; q++) {
        f32x4 pv, sv;
#pragma unroll
        for (int k = 0; k < 4; k++) { pv[k] = p[q*4+k]; sv[k] = s[q*4+k]; }
        *reinterpret_cast<f32x4*>(&P[o + q * 4]) = pv;
        *reinterpret_cast<f32x4*>(&S[o + q * 4]) = sv;
    }
}

// ---------------- kernel C: inter-chunk scan; H0 overwrites S in place ------
// batched-8 loads, 1-deep double buffer: 16 loads in flight across the chain
__global__ __launch_bounds__(64) void k_scan_chunks(
        const float* __restrict__ P, float* __restrict__ S_H0)
{
    int b = blockIdx.x >> 6, seg = blockIdx.x & 63;
    size_t base = (size_t)b * NC * 4096 + seg * 64 + threadIdx.x;
    float pv[8], sv[8], pn[8], sn[8];
#pragma unroll
    for (int k = 0; k < 8; k++) { pv[k] = P[base + k * 4096]; sv[k] = S_H0[base + k * 4096]; }
    float h = 0.f;
    for (int cb = 0; cb < NC / 8; cb++) {
        size_t cbase = base + (size_t)cb * 8 * 4096;
        if (cb + 1 < NC / 8) {
            size_t nbase = cbase + 8 * 4096;
#pragma unroll
            for (int k = 0; k < 8; k++) { pn[k] = P[nbase + k * 4096]; sn[k] = S_H0[nbase + k * 4096]; }
        }
        float hp[8];
#pragma unroll
        for (int k = 0; k < 8; k++) { hp[k] = h; h = fmaf(pv[k], h, sv[k]); }
#pragma unroll
        for (int k = 0; k < 8; k++) S_H0[cbase + k * 4096] = hp[k];
#pragma unroll
        for (int k = 0; k < 8; k++) { pv[k] = pn[k]; sv[k] = sn[k]; }
    }
}

// ---------------- kernel D: re-scan + DFT(MFMA) + mix + inverse + epilogue --
// one block per 16-row chunk; h never touches HBM.
__global__ __launch_bounds__(256) void k_fused(
        const float* __restrict__ delta, const float* __restrict__ xn,
        const float* __restrict__ Bc, const float* __restrict__ Cc,
        const float* __restrict__ A_neg, const float* __restrict__ H0,
        const float* __restrict__ w_re, const float* __restrict__ w_im,
        const float* __restrict__ base, float* __restrict__ out)
{
    __shared__ __align__(16) char smem[55808];
    // a_lds: 32768B bf16 A-tile [64 m][256 d] (XOR-swizzled); gpart overlays it at the end
    float* gpart = (float*)smem;                         // [8 oq][32 x][16 r][2]
    float* hf_s  = (float*)(smem + 32768);               // [4 mt][16 i][66]
    float* g_s   = (float*)(smem + 32768 + 16896);       // [16 r][32 x][2]
    float* cc_s  = (float*)(smem + 53760);               // [16 r][16 o]
    float* bc_s  = (float*)(smem + 54784);               // [16 t][16 n]
    int tid = threadIdx.x, wave = tid >> 6, lane = tid & 63;
    int blk = blockIdx.x;
    int grow0 = blk * CL;
    int d = tid;

    cc_s[tid] = Cc[(size_t)grow0 * 16 + tid];
    bc_s[tid] = Bc[(size_t)grow0 * 16 + tid];

    // B fragments: E[dd][xx]; xx<32: cos, xx>=32: -sin (Re / Im of rfft)
    int xx = wave * 16 + (lane & 15);
    bf16x8 bfrag[8];
#pragma unroll
    for (int ks = 0; ks < 8; ks++) {
#pragma unroll
        for (int j = 0; j < 8; j++) {
            int dd = ks * 32 + ((lane >> 4) * 8) + j;
            float val;
            if (xx < 32) val =  __cosf(ANG * (float)((xx * dd) & 255));
            else         val = -__sinf(ANG * (float)(((xx - 32) * dd) & 255));
            bfrag[ks][j] = (__bf16)val;
        }
    }
    float ar[16], h[16];
    {
        size_t ho = (size_t)blk * 4096 + d * 16;
#pragma unroll
        for (int q = 0; q < 4; q++) {
            f32x4 a4 = *(const f32x4*)&A_neg[d * 16 + q * 4];
            f32x4 h4 = *(const f32x4*)&H0[ho + q * 4];
#pragma unroll
            for (int k = 0; k < 4; k++) { ar[q*4+k] = a4[k]; h[q*4+k] = h4[k]; }
        }
    }
    float gre[16], gim[16];
#pragma unroll
    for (int r = 0; r < 16; r++) { gre[r] = 0.f; gim[r] = 0.f; }
    int x = tid & 31, oq = tid >> 5;
    int swz = (lane & 7) << 4;
    __syncthreads();   // cc_s / bc_s ready

#pragma unroll
    for (int g = 0; g < 4; g++) {
        // --- scan 4 timesteps into swizzled A-tile ---
#pragma unroll
        for (int tl = 0; tl < 4; tl++) {
            int t = g * 4 + tl;
            size_t grow = grow0 + t;
            float dlt = delta[grow * D_ + d];
            float dx  = dlt * xn[grow * D_ + d];
#pragma unroll
            for (int n = 0; n < 16; n++) {
                float e = __expf(dlt * ar[n]);
                h[n] = fmaf(e, h[n], dx * bc_s[t * 16 + n]);
                int m = tl * 16 + n;
                int byte = m * 512 + ((d * 2) ^ ((m & 7) << 4));
                *(__bf16*)(smem + byte) = (__bf16)h[n];
            }
        }
        __syncthreads();
        // --- MFMA: hf[m][xx] = sum_d A[m][d] * E[d][xx] ---
        f32x4 acc[4];
#pragma unroll
        for (int mt = 0; mt < 4; mt++) { acc[mt][0]=0.f; acc[mt][1]=0.f; acc[mt][2]=0.f; acc[mt][3]=0.f; }
#pragma unroll
        for (int ks = 0; ks < 8; ks++) {
#pragma unroll
            for (int mt = 0; mt < 4; mt++) {
                int m = mt * 16 + (lane & 15);
                int byte = m * 512 + ((ks * 64 + ((lane >> 4) * 16)) ^ swz);
                bf16x8 af = *(const bf16x8*)(smem + byte);
                acc[mt] = __builtin_amdgcn_mfma_f32_16x16x32_bf16(af, bfrag[ks], acc[mt], 0, 0, 0);
            }
        }
        // C/D layout: col = lane&15 (-> xx), row = (lane>>4)*4+q (= state i)
#pragma unroll
        for (int mt = 0; mt < 4; mt++) {
#pragma unroll
            for (int q = 0; q < 4; q++) {
                int i = (lane >> 4) * 4 + q;
                hf_s[mt * 1056 + i * 66 + xx] = acc[mt][q];
            }
        }
        __syncthreads();
        // --- mix rows g*4..g*4+3: g[r] += Cc[o] * (hf . w)  (thread = (x, 2 o's)) ---
#pragma unroll
        for (int i = 0; i < 16; i++) {
            float hr[4], hi[4];
#pragma unroll
            for (int r = 0; r < 4; r++) {
                hr[r] = hf_s[r * 1056 + i * 66 + x];
                hi[r] = hf_s[r * 1056 + i * 66 + 32 + x];
            }
#pragma unroll
            for (int oo = 0; oo < 2; oo++) {
                int o = oq * 2 + oo;
                float wre = w_re[(i * 16 + o) * 32 + x];
                float wim = w_im[(i * 16 + o) * 32 + x];
#pragma unroll
                for (int r = 0; r < 4; r++) {
                    int gr = g * 4 + r;
                    float cc = cc_s[gr * 16 + o];
                    gre[gr] = fmaf(cc, hr[r] * wre - hi[r] * wim, gre[gr]);
                    gim[gr] = fmaf(cc, hr[r] * wim + hi[r] * wre, gim[gr]);
                }
            }
        }
        // next gulp's post-scan barrier orders a_lds rewrite & hf_s rewrite vs this mix
    }
    // --- reduce the 8 oq-partials (through dead A-tile region) ---
#pragma unroll
    for (int gr = 0; gr < 16; gr++) {
        gpart[((oq * 32 + x) * 16 + gr) * 2 + 0] = gre[gr];
        gpart[((oq * 32 + x) * 16 + gr) * 2 + 1] = gim[gr];
    }
    __syncthreads();
#pragma unroll
    for (int it = tid; it < 512; it += 256) {
        int gr = it >> 5, xm = it & 31;
        float sre = 0.f, sim = 0.f;
#pragma unroll
        for (int q = 0; q < 8; q++) {
            sre += gpart[((q * 32 + xm) * 16 + gr) * 2 + 0];
            sim += gpart[((q * 32 + xm) * 16 + gr) * 2 + 1];
        }
        g_s[(gr * 32 + xm) * 2 + 0] = sre;
        g_s[(gr * 32 + xm) * 2 + 1] = sim;
    }
    __syncthreads();
    // --- inverse (32 modes) + epilogue ---
    float cph[31], sph[31];
#pragma unroll
    for (int xm = 1; xm < 32; xm++) {
        float a = ANG * (float)((xm * d) & 255);
        cph[xm-1] = __cosf(a); sph[xm-1] = __sinf(a);
    }
#pragma unroll
    for (int gr = 0; gr < 16; gr++) {
        float a4 = 0.f;
#pragma unroll
        for (int xm = 1; xm < 32; xm++)
            a4 += g_s[(gr * 32 + xm) * 2] * cph[xm-1] - g_s[(gr * 32 + xm) * 2 + 1] * sph[xm-1];
        size_t grow = grow0 + gr;
        out[grow * D_ + d] = base[grow * D_ + d] + (g_s[gr * 64] + 2.f * a4) * (1.f / 256.f);
    }
}

// ---------------- launch -----------------------------------------------------
extern "C" void kernel_launch(void* const* d_in, const int* in_sizes, int n_in,
                              void* d_out, int out_size, void* d_ws, size_t ws_size,
                              hipStream_t stream)
{
    const float* x       = (const float*)d_in[0];
    const float* ln_g    = (const float*)d_in[1];
    const float* ln_b    = (const float*)d_in[2];
    const float* W_xproj = (const float*)d_in[3];
    const float* W_dt    = (const float*)d_in[4];
    const float* b_dt    = (const float*)d_in[5];
    const float* A_log   = (const float*)d_in[6];
    const float* D_param = (const float*)d_in[7];
    const float* w_re    = (const float*)d_in[8];
    const float* w_im    = (const float*)d_in[9];

    // workspace layout (floats) — total ~43 MB
    float* ws    = (float*)d_ws;
    float* A_neg = ws;                         // 4096
    float* xn    = A_neg + 4096;               // 2M
    float* delta = xn + 2097152;               // 2M
    float* base  = delta + 2097152;            // 2M
    float* Bc    = base + 2097152;             // 131072
    float* Cc    = Bc + 131072;                // 131072
    float* S_H0  = Cc + 131072;                // 2M (S, then H0 in place)
    float* P     = S_H0 + 2097152;             // 2M
    float* out = (float*)d_out;

    hipLaunchKernelGGL(k_prep,        dim3(16),      dim3(256), 0, stream, A_log, A_neg);
    hipLaunchKernelGGL(k_lnscan,      dim3(B_*NC),   dim3(256), 0, stream,
                       x, ln_g, ln_b, W_xproj, W_dt, b_dt, D_param, A_neg,
                       xn, delta, base, Bc, Cc, P, S_H0);
    hipLaunchKernelGGL(k_scan_chunks, dim3(256),     dim3(64),  0, stream, P, S_H0);
    hipLaunchKernelGGL(k_fused,       dim3(B_*NC),   dim3(256), 0, stream,
                       delta, xn, Bc, Cc, A_neg, S_H0, w_re, w_im, base, out);
}

// Round 4
// 96.446 us; speedup vs baseline: 4.2611x; 1.5320x over previous
//
#include <hip/hip_runtime.h>
#include <hip/hip_bf16.h>

// Problem constants
#define B_   4
#define L_   2048
#define D_   256
#define NC   128
#define CL   16
#define ANG  0.02454369260617025967f   // 2*pi/256

typedef __bf16 bf16x8 __attribute__((ext_vector_type(8)));
typedef float  f32x4  __attribute__((ext_vector_type(4)));

// ===== kernel 1: LN + proj + delta + local scan (per 16-row chunk) =====
__global__ __launch_bounds__(256) void k_lnscan(
        const float* __restrict__ x, const float* __restrict__ ln_g, const float* __restrict__ ln_b,
        const float* __restrict__ W_xproj, const float* __restrict__ W_dt,
        const float* __restrict__ b_dt, const float* __restrict__ D_param,
        const float* __restrict__ A_log,
        float* __restrict__ xn_o, float* __restrict__ delta_o, float* __restrict__ base_o,
        float* __restrict__ Bc_o, float* __restrict__ Cc_o,
        float* __restrict__ P, float* __restrict__ S)
{
    __shared__ __align__(16) float w_lds[48 * 256];   // W_xproj staged once per block
    __shared__ __align__(16) float xn_s[16 * 260];    // stride 260 (65 dw) -> conflict-free
    __shared__ float dbc_s[16 * 52];
    int tid = threadIdx.x, wave = tid >> 6, lane = tid & 63;
    int blk = blockIdx.x;
    int grow0 = blk * CL;

    {   // stage W_xproj: 12288 floats, f32x4 coalesced
        f32x4* wl = (f32x4*)w_lds;
        const f32x4* wg = (const f32x4*)W_xproj;
#pragma unroll
        for (int i = 0; i < 12; i++) wl[i * 256 + tid] = wg[i * 256 + tid];
    }
    // --- Phase A: LayerNorm, 4 rows per wave ---
#pragma unroll
    for (int rr = 0; rr < 4; rr++) {
        int r = wave * 4 + rr;
        const float* xr = x + (size_t)(grow0 + r) * D_;
        float v[4];
#pragma unroll
        for (int q = 0; q < 4; q++) v[q] = xr[lane + q * 64];
        float sum = v[0] + v[1] + v[2] + v[3];
        float sq  = v[0]*v[0] + v[1]*v[1] + v[2]*v[2] + v[3]*v[3];
#pragma unroll
        for (int off = 32; off; off >>= 1) { sum += __shfl_xor(sum, off); sq += __shfl_xor(sq, off); }
        float mu = sum * (1.f / D_);
        float rstd = rsqrtf(sq * (1.f / D_) - mu * mu + 1e-5f);
#pragma unroll
        for (int q = 0; q < 4; q++) {
            int d = lane + q * 64;
            float xv = (v[q] - mu) * rstd * ln_g[d] + ln_b[d];
            xn_s[r * 260 + d] = xv;
            xn_o[(size_t)(grow0 + r) * D_ + d] = xv;
            base_o[(size_t)(grow0 + r) * D_ + d] = v[q] + D_param[d] * xv;
        }
    }
    __syncthreads();

    // --- Phase B: dbc[row][j] = xn[row] . W[j]; thread = (row, 3 j's); w from LDS (broadcast) ---
    {
        int row = tid & 15, jg = tid >> 4;
        const f32x4* xs4 = (const f32x4*)&xn_s[row * 260];
        const f32x4* w0 = (const f32x4*)&w_lds[(jg * 3 + 0) * 256];
        const f32x4* w1 = (const f32x4*)&w_lds[(jg * 3 + 1) * 256];
        const f32x4* w2 = (const f32x4*)&w_lds[(jg * 3 + 2) * 256];
        float a0 = 0.f, a1 = 0.f, a2 = 0.f;
        for (int e4 = 0; e4 < 64; e4++) {
            f32x4 xv = xs4[e4];
            f32x4 wa = w0[e4], wb = w1[e4], wc = w2[e4];
#pragma unroll
            for (int k = 0; k < 4; k++) {
                a0 = fmaf(xv[k], wa[k], a0);
                a1 = fmaf(xv[k], wb[k], a1);
                a2 = fmaf(xv[k], wc[k], a2);
            }
        }
        float av[3] = {a0, a1, a2};
        int grow = grow0 + row;
#pragma unroll
        for (int jj = 0; jj < 3; jj++) {
            int j = jg * 3 + jj;
            dbc_s[row * 52 + j] = av[jj];
            if (j >= 32)      Cc_o[(size_t)grow * 16 + j - 32] = av[jj];
            else if (j >= 16) Bc_o[(size_t)grow * 16 + j - 16] = av[jj];
        }
    }
    __syncthreads();

    // --- Phase C: delta = softplus(dbc[:16] . W_dt[d] + b_dt[d]) ---
    int d = tid;
    float wdt[16];
#pragma unroll
    for (int q = 0; q < 4; q++) {
        f32x4 w4 = *(const f32x4*)&W_dt[d * 16 + q * 4];
#pragma unroll
        for (int k = 0; k < 4; k++) wdt[q * 4 + k] = w4[k];
    }
    float bd = b_dt[d];
    float dlt_r[16];
#pragma unroll
    for (int r = 0; r < 16; r++) {
        float din = bd;
#pragma unroll
        for (int k = 0; k < 16; k++) din = fmaf(dbc_s[r * 52 + k], wdt[k], din);
        din = (din > 15.f) ? din : log1pf(__expf(din));
        dlt_r[r] = din;
        delta_o[(size_t)(grow0 + r) * D_ + d] = din;
    }

    // --- Phase D: local scan over 16 timesteps (A from A_log inline) ---
    float ar[16], p[16], s[16];
#pragma unroll
    for (int q = 0; q < 4; q++) {
        f32x4 a4 = *(const f32x4*)&A_log[d * 16 + q * 4];
#pragma unroll
        for (int k = 0; k < 4; k++) { ar[q*4+k] = -__expf(a4[k]); p[q*4+k] = 1.f; s[q*4+k] = 0.f; }
    }
#pragma unroll
    for (int t = 0; t < CL; t++) {
        float dlt = dlt_r[t];
        float dx  = dlt * xn_s[t * 260 + d];
#pragma unroll
        for (int n = 0; n < 16; n++) {
            float e = __expf(dlt * ar[n]);
            s[n] = fmaf(e, s[n], dx * dbc_s[t * 52 + 16 + n]);
            p[n] *= e;
        }
    }
    size_t o = (size_t)blk * 4096 + d * 16;
#pragma unroll
    for (int q = 0; q < 4; q++) {
        f32x4 pv, sv;
#pragma unroll
        for (int k = 0; k < 4; k++) { pv[k] = p[q*4+k]; sv[k] = s[q*4+k]; }
        *reinterpret_cast<f32x4*>(&P[o + q * 4]) = pv;
        *reinterpret_cast<f32x4*>(&S[o + q * 4]) = sv;
    }
}

// ===== kernel 2: inter-chunk scan; H0 overwrites S in place =====
__global__ __launch_bounds__(64) void k_scan_chunks(
        const float* __restrict__ P, float* __restrict__ S_H0)
{
    int b = blockIdx.x >> 6, seg = blockIdx.x & 63;
    size_t base = (size_t)b * NC * 4096 + seg * 64 + threadIdx.x;
    float pv[8], sv[8], pn[8], sn[8];
#pragma unroll
    for (int k = 0; k < 8; k++) { pv[k] = P[base + k * 4096]; sv[k] = S_H0[base + k * 4096]; }
    float h = 0.f;
    for (int cb = 0; cb < NC / 8; cb++) {
        size_t cbase = base + (size_t)cb * 8 * 4096;
        if (cb + 1 < NC / 8) {
            size_t nbase = cbase + 8 * 4096;
#pragma unroll
            for (int k = 0; k < 8; k++) { pn[k] = P[nbase + k * 4096]; sn[k] = S_H0[nbase + k * 4096]; }
        }
        float hp[8];
#pragma unroll
        for (int k = 0; k < 8; k++) { hp[k] = h; h = fmaf(pv[k], h, sv[k]); }
#pragma unroll
        for (int k = 0; k < 8; k++) S_H0[cbase + k * 4096] = hp[k];
#pragma unroll
        for (int k = 0; k < 8; k++) { pv[k] = pn[k]; sv[k] = sn[k]; }
    }
}

// ===== kernel 3: re-scan + DFT(MFMA) + mix + inverse + epilogue =====
// LDS map:
//   [0, 32768)      A-tile bf16 [64m][256d] swizzled;  gpart f32 [256 slots][33] after mix
//   [32768, 66560)  hf bf16 [16r][16i][66x]
//   [66560, 70656)  g_s f32 [16r][32x][2]
//   [70656, 71680)  cc_s; [71680, 72704) bc_s
__global__ __launch_bounds__(256, 2) void k_fused(
        const float* __restrict__ delta, const float* __restrict__ xn,
        const float* __restrict__ Bc, const float* __restrict__ Cc,
        const float* __restrict__ A_log, const float* __restrict__ H0,
        const float* __restrict__ w_re, const float* __restrict__ w_im,
        const float* __restrict__ base, float* __restrict__ out)
{
    __shared__ __align__(16) char smem[72704];
    __bf16* hfb  = (__bf16*)(smem + 32768);
    float* g_s   = (float*)(smem + 66560);
    float* cc_s  = (float*)(smem + 70656);
    float* bc_s  = (float*)(smem + 71680);
    float* gpart = (float*)smem;

    int tid = threadIdx.x, wave = tid >> 6, lane = tid & 63;
    int blk = blockIdx.x;
    int grow0 = blk * CL;
    int d = tid;

    // ---- all global loads issued up front ----
    bc_s[tid] = Bc[(size_t)grow0 * 16 + tid];
    cc_s[tid] = Cc[(size_t)grow0 * 16 + tid];
    float dlt[16], dxv[16];
#pragma unroll
    for (int t = 0; t < 16; t++) {
        dlt[t] = delta[(size_t)(grow0 + t) * D_ + d];
        dxv[t] = xn[(size_t)(grow0 + t) * D_ + d];
    }
    float ar[16], h[16];
    {
        size_t ho = (size_t)blk * 4096 + d * 16;
#pragma unroll
        for (int q = 0; q < 4; q++) {
            f32x4 a4 = *(const f32x4*)&A_log[d * 16 + q * 4];
            f32x4 h4 = *(const f32x4*)&H0[ho + q * 4];
#pragma unroll
            for (int k = 0; k < 4; k++) { ar[q*4+k] = -__expf(a4[k]); h[q*4+k] = h4[k]; }
        }
    }
    // ---- B fragments: E[dd][xx]; xx<32: cos, xx>=32: -sin ----
    int xx = wave * 16 + (lane & 15);
    bf16x8 bfrag[8];
#pragma unroll
    for (int ks = 0; ks < 8; ks++) {
#pragma unroll
        for (int j = 0; j < 8; j++) {
            int dd = ks * 32 + ((lane >> 4) * 8) + j;
            float val;
            if (xx < 32) val =  __cosf(ANG * (float)((xx * dd) & 255));
            else         val = -__sinf(ANG * (float)(((xx - 32) * dd) & 255));
            bfrag[ks][j] = (__bf16)val;
        }
    }
    int swz = (lane & 7) << 4;
    __syncthreads();   // bc_s/cc_s ready

    // ---- 4 gulps: scan -> A-tile; MFMA -> hf (bf16 LDS) ----
#pragma unroll
    for (int g = 0; g < 4; g++) {
#pragma unroll
        for (int tl = 0; tl < 4; tl++) {
            int t = g * 4 + tl;
            float dl = dlt[t];
            float dx = dl * dxv[t];
#pragma unroll
            for (int n = 0; n < 16; n++) {
                float e = __expf(dl * ar[n]);
                h[n] = fmaf(e, h[n], dx * bc_s[t * 16 + n]);
                int m = tl * 16 + n;
                *(__bf16*)(smem + m * 512 + ((d * 2) ^ ((m & 7) << 4))) = (__bf16)h[n];
            }
        }
        __syncthreads();
        f32x4 acc[4];
#pragma unroll
        for (int mt = 0; mt < 4; mt++) { acc[mt][0]=0.f; acc[mt][1]=0.f; acc[mt][2]=0.f; acc[mt][3]=0.f; }
#pragma unroll
        for (int ks = 0; ks < 8; ks++) {
#pragma unroll
            for (int mt = 0; mt < 4; mt++) {
                int m = mt * 16 + (lane & 15);
                bf16x8 af = *(const bf16x8*)(smem + m * 512 + ((ks * 64 + ((lane >> 4) * 16)) ^ swz));
                acc[mt] = __builtin_amdgcn_mfma_f32_16x16x32_bf16(af, bfrag[ks], acc[mt], 0, 0, 0);
            }
        }
        // store hf: C/D layout col=lane&15 (->xx), row=(lane>>4)*4+q (= state i)
#pragma unroll
        for (int mt = 0; mt < 4; mt++) {
            int r = g * 4 + mt;
#pragma unroll
            for (int q = 0; q < 4; q++) {
                int i = (lane >> 4) * 4 + q;
                hfb[(r * 16 + i) * 66 + xx] = (__bf16)acc[mt][q];
            }
        }
        __syncthreads();
    }

    // ---- base prefetch (latency hides under mix) ----
    float bsv[16];
#pragma unroll
    for (int r = 0; r < 16; r++) bsv[r] = base[(size_t)(grow0 + r) * D_ + d];

    // ---- mix: thread = (x 0..31, oq 0..7 o-pairs); g[r] += Cc[r,o]*(hf . w) ----
    int x = tid & 31, oq = tid >> 5;
    float ccr0[16], ccr1[16];
#pragma unroll
    for (int r = 0; r < 16; r++) { ccr0[r] = cc_s[r * 16 + oq * 2]; ccr1[r] = cc_s[r * 16 + oq * 2 + 1]; }
    float gre[16], gim[16];
#pragma unroll
    for (int r = 0; r < 16; r++) { gre[r] = 0.f; gim[r] = 0.f; }
    for (int i = 0; i < 16; i++) {
        int wo = (i * 16 + oq * 2) * 32 + x;
        float wre0 = w_re[wo], wim0 = w_im[wo];
        float wre1 = w_re[wo + 32], wim1 = w_im[wo + 32];
#pragma unroll
        for (int r = 0; r < 16; r++) {
            float hr = (float)hfb[(r * 16 + i) * 66 + x];
            float hi = (float)hfb[(r * 16 + i) * 66 + 32 + x];
            float t0re = hr * wre0 - hi * wim0;
            float t0im = hr * wim0 + hi * wre0;
            float t1re = hr * wre1 - hi * wim1;
            float t1im = hr * wim1 + hi * wre1;
            gre[r] = fmaf(ccr0[r], t0re, gre[r]);
            gim[r] = fmaf(ccr0[r], t0im, gim[r]);
            gre[r] = fmaf(ccr1[r], t1re, gre[r]);
            gim[r] = fmaf(ccr1[r], t1im, gim[r]);
        }
    }
    __syncthreads();   // all hf reads done -> gpart may overwrite A/hf head
    {
        float* gp = gpart + (oq * 32 + x) * 33;   // stride 33 -> bank = x, conflict-free
#pragma unroll
        for (int r = 0; r < 16; r++) { gp[r * 2] = gre[r]; gp[r * 2 + 1] = gim[r]; }
    }
    __syncthreads();
    // ---- reduce 8 oq-partials -> g_s (pre-scaled by 2 for x>0) ----
#pragma unroll
    for (int it = tid; it < 512; it += 256) {
        int gr = it >> 5, xm = it & 31;
        float sre = 0.f, sim = 0.f;
#pragma unroll
        for (int q = 0; q < 8; q++) {
            const float* gp = gpart + (q * 32 + xm) * 33 + gr * 2;
            sre += gp[0]; sim += gp[1];
        }
        float sc = (xm == 0) ? 1.f : 2.f;
        g_s[gr * 64 + xm * 2]     = sre * sc;
        g_s[gr * 64 + xm * 2 + 1] = sim * sc;
    }
    __syncthreads();
    // ---- inverse via phase recurrence + epilogue ----
    float s1, c1;
    __sincosf(ANG * (float)d, &s1, &c1);
    float cx = c1, sx = s1;
    float acc[16];
#pragma unroll
    for (int gr = 0; gr < 16; gr++) acc[gr] = g_s[gr * 64];   // x=0, re
    for (int xm = 1; xm < 32; xm++) {
#pragma unroll
        for (int gr = 0; gr < 16; gr++) {
            acc[gr] = fmaf(g_s[gr * 64 + xm * 2], cx, acc[gr]);
            acc[gr] = fmaf(-g_s[gr * 64 + xm * 2 + 1], sx, acc[gr]);
        }
        float cn = cx * c1 - sx * s1;
        sx = sx * c1 + cx * s1;
        cx = cn;
    }
#pragma unroll
    for (int gr = 0; gr < 16; gr++)
        out[(size_t)(grow0 + gr) * D_ + d] = bsv[gr] + acc[gr] * (1.f / 256.f);
}

// ===== launch =====
extern "C" void kernel_launch(void* const* d_in, const int* in_sizes, int n_in,
                              void* d_out, int out_size, void* d_ws, size_t ws_size,
                              hipStream_t stream)
{
    const float* x       = (const float*)d_in[0];
    const float* ln_g    = (const float*)d_in[1];
    const float* ln_b    = (const float*)d_in[2];
    const float* W_xproj = (const float*)d_in[3];
    const float* W_dt    = (const float*)d_in[4];
    const float* b_dt    = (const float*)d_in[5];
    const float* A_log   = (const float*)d_in[6];
    const float* D_param = (const float*)d_in[7];
    const float* w_re    = (const float*)d_in[8];
    const float* w_im    = (const float*)d_in[9];

    float* ws    = (float*)d_ws;
    float* xn    = ws;                         // 2M
    float* delta = xn + 2097152;               // 2M
    float* base  = delta + 2097152;            // 2M
    float* Bc    = base + 2097152;             // 131072
    float* Cc    = Bc + 131072;                // 131072
    float* S_H0  = Cc + 131072;                // 2M (S, then H0 in place)
    float* P     = S_H0 + 2097152;             // 2M
    float* out = (float*)d_out;

    hipLaunchKernelGGL(k_lnscan,      dim3(B_*NC), dim3(256), 0, stream,
                       x, ln_g, ln_b, W_xproj, W_dt, b_dt, D_param, A_log,
                       xn, delta, base, Bc, Cc, P, S_H0);
    hipLaunchKernelGGL(k_scan_chunks, dim3(256),   dim3(64),  0, stream, P, S_H0);
    hipLaunchKernelGGL(k_fused,       dim3(B_*NC), dim3(256), 0, stream,
                       delta, xn, Bc, Cc, A_log, S_H0, w_re, w_im, base, out);
}

// Round 5
// 63.525 us; speedup vs baseline: 6.4693x; 1.5182x over previous
//
#include <hip/hip_runtime.h>
#include <hip/hip_bf16.h>

// Problem constants
#define B_   4
#define L_   2048
#define D_   256
#define NC   128
#define CL   16
#define ANG  0.02454369260617025967f   // 2*pi/256

typedef __bf16 bf16x8 __attribute__((ext_vector_type(8)));
typedef float  f32x4  __attribute__((ext_vector_type(4)));

// ===== kernel 0: build bf16 fragment tables (per-call, cheap) =====
// E_t   [64 x][256 d]      : x<32 -> cos(theta*x*d), else -sin(theta*(x-32)*d)
// Wfrag [8 ks][256 tid][8 j]: B-frags for dbc MFMA (B[k=d][n=j] = W_xproj^T, j>=48 -> 0)
// wfrag [64 nt][64 l][8 j] : B-frags for wc MFMA   (B[k=o'][n=(i,comp,x)], o'>=16 -> 0)
// E_inv [16 nt][2 ks][64 l][8 j]: B-frags for inverse MFMA (B[k][d'] = E_t[k][d'])
__global__ __launch_bounds__(256) void k_prep(
        const float* __restrict__ W_xproj, const float* __restrict__ w_re, const float* __restrict__ w_im,
        __hip_bfloat16* __restrict__ E_t, __hip_bfloat16* __restrict__ Wfrag,
        __hip_bfloat16* __restrict__ wfrag, __hip_bfloat16* __restrict__ E_inv)
{
    int idx = blockIdx.x * 256 + threadIdx.x;
    if (idx < 16384) {
        int x = idx >> 8, d = idx & 255;
        float v = (x < 32) ? __cosf(ANG * (float)((x * d) & 255))
                           : -__sinf(ANG * (float)(((x - 32) * d) & 255));
        E_t[idx] = __float2bfloat16(v);
    } else if (idx < 32768) {
        int f = idx - 16384;
        int ks = f >> 11, t = (f >> 3) & 255, j = f & 7;
        int jcol = (t >> 6) * 16 + (t & 15);
        int dd = ks * 32 + ((t >> 4) & 3) * 8 + j;
        float v = (jcol < 48) ? W_xproj[jcol * 256 + dd] : 0.f;
        Wfrag[f] = __float2bfloat16(v);
    } else if (idx < 65536) {
        int f = idx - 32768;
        int nt = f >> 9, l = (f >> 3) & 63, j = f & 7;
        int n = nt * 16 + (l & 15);
        int o = ((l >> 4) & 3) * 8 + j;          // k = o' 0..31
        float v = 0.f;
        if (o < 16) {
            int i = n >> 6, comp = (n >> 5) & 1, x = n & 31;
            v = comp ? w_im[(i * 16 + o) * 32 + x] : w_re[(i * 16 + o) * 32 + x];
        }
        wfrag[f] = __float2bfloat16(v);
    } else if (idx < 81920) {
        int f = idx - 65536;
        int nt = f >> 10, ks = (f >> 9) & 1, l = (f >> 3) & 63, j = f & 7;
        int row = ks * 32 + ((l >> 4) & 3) * 8 + j;
        int col = nt * 16 + (l & 15);
        float v = (row < 32) ? __cosf(ANG * (float)((row * col) & 255))
                             : -__sinf(ANG * (float)(((row - 32) * col) & 255));
        E_inv[f] = __float2bfloat16(v);
    }
}

// ===== kernel 1: LN + proj(MFMA) + delta + local scan (per 16-row chunk) =====
__global__ __launch_bounds__(256) void k_lnscan(
        const float* __restrict__ x, const float* __restrict__ ln_g, const float* __restrict__ ln_b,
        const float* __restrict__ W_dt, const float* __restrict__ b_dt,
        const float* __restrict__ D_param, const float* __restrict__ A_log,
        const __hip_bfloat16* __restrict__ Wfrag,
        float* __restrict__ xn_o, float* __restrict__ delta_o, float* __restrict__ base_o,
        float* __restrict__ Bc_o, float* __restrict__ Cc_o,
        float* __restrict__ P, float* __restrict__ S)
{
    __shared__ __align__(16) float xn_s[16 * 260];   // f32, stride 260 -> conflict-free
    __shared__ __align__(16) __bf16 xnb[16 * 256];   // bf16 A-tile [m][d], XOR-swizzled
    __shared__ float dbc_s[16 * 52];
    int tid = threadIdx.x, wave = tid >> 6, lane = tid & 63;
    int blk = blockIdx.x;
    int grow0 = blk * CL;
    char* xnb_c = (char*)xnb;

    // --- Phase A: LayerNorm, 4 rows per wave ---
#pragma unroll
    for (int rr = 0; rr < 4; rr++) {
        int r = wave * 4 + rr;
        const float* xr = x + (size_t)(grow0 + r) * D_;
        float v[4];
#pragma unroll
        for (int q = 0; q < 4; q++) v[q] = xr[lane + q * 64];
        float sum = v[0] + v[1] + v[2] + v[3];
        float sq  = v[0]*v[0] + v[1]*v[1] + v[2]*v[2] + v[3]*v[3];
#pragma unroll
        for (int off = 32; off; off >>= 1) { sum += __shfl_xor(sum, off); sq += __shfl_xor(sq, off); }
        float mu = sum * (1.f / D_);
        float rstd = rsqrtf(sq * (1.f / D_) - mu * mu + 1e-5f);
#pragma unroll
        for (int q = 0; q < 4; q++) {
            int d = lane + q * 64;
            float xv = (v[q] - mu) * rstd * ln_g[d] + ln_b[d];
            xn_s[r * 260 + d] = xv;
            *(__bf16*)(xnb_c + r * 512 + ((d * 2) ^ ((r & 7) << 4))) = (__bf16)xv;
            xn_o[(size_t)(grow0 + r) * D_ + d] = xv;
            base_o[(size_t)(grow0 + r) * D_ + d] = v[q] + D_param[d] * xv;
        }
    }
    __syncthreads();

    // --- Phase B: dbc = xn @ W_xproj^T via MFMA (M=16 rows, N=64 j, K=256) ---
    {
        int mrow = lane & 15;
        f32x4 acc = {0.f, 0.f, 0.f, 0.f};
#pragma unroll
        for (int ks = 0; ks < 8; ks++) {
            bf16x8 af = *(const bf16x8*)(xnb_c + mrow * 512 +
                          ((ks * 64 + ((lane >> 4) * 16)) ^ ((mrow & 7) << 4)));
            bf16x8 bf = *(const bf16x8*)(Wfrag + (ks * 256 + tid) * 8);
            acc = __builtin_amdgcn_mfma_f32_16x16x32_bf16(af, bf, acc, 0, 0, 0);
        }
        int j = wave * 16 + (lane & 15);
#pragma unroll
        for (int q = 0; q < 4; q++) {
            int r = (lane >> 4) * 4 + q;
            if (j < 48) dbc_s[r * 52 + j] = acc[q];
            if (j >= 32 && j < 48)      Cc_o[(size_t)(grow0 + r) * 16 + j - 32] = acc[q];
            else if (j >= 16 && j < 32) Bc_o[(size_t)(grow0 + r) * 16 + j - 16] = acc[q];
        }
    }
    __syncthreads();

    // --- Phase C: delta = softplus(dbc[:16] . W_dt[d] + b_dt[d]) ---
    int d = tid;
    float wdt[16];
#pragma unroll
    for (int q = 0; q < 4; q++) {
        f32x4 w4 = *(const f32x4*)&W_dt[d * 16 + q * 4];
#pragma unroll
        for (int k = 0; k < 4; k++) wdt[q * 4 + k] = w4[k];
    }
    float bd = b_dt[d];
    float dlt_r[16];
#pragma unroll
    for (int r = 0; r < 16; r++) {
        float din = bd;
#pragma unroll
        for (int k = 0; k < 16; k++) din = fmaf(dbc_s[r * 52 + k], wdt[k], din);
        din = (din > 15.f) ? din : log1pf(__expf(din));
        dlt_r[r] = din;
        delta_o[(size_t)(grow0 + r) * D_ + d] = din;
    }

    // --- Phase D: local scan over 16 timesteps ---
    float ar[16], p[16], s[16];
#pragma unroll
    for (int q = 0; q < 4; q++) {
        f32x4 a4 = *(const f32x4*)&A_log[d * 16 + q * 4];
#pragma unroll
        for (int k = 0; k < 4; k++) { ar[q*4+k] = -__expf(a4[k]); p[q*4+k] = 1.f; s[q*4+k] = 0.f; }
    }
#pragma unroll
    for (int t = 0; t < CL; t++) {
        float dlt = dlt_r[t];
        float dx  = dlt * xn_s[t * 260 + d];
#pragma unroll
        for (int n = 0; n < 16; n++) {
            float e = __expf(dlt * ar[n]);
            s[n] = fmaf(e, s[n], dx * dbc_s[t * 52 + 16 + n]);
            p[n] *= e;
        }
    }
    size_t o = (size_t)blk * 4096 + d * 16;
#pragma unroll
    for (int q = 0; q < 4; q++) {
        f32x4 pv, sv;
#pragma unroll
        for (int k = 0; k < 4; k++) { pv[k] = p[q*4+k]; sv[k] = s[q*4+k]; }
        *reinterpret_cast<f32x4*>(&P[o + q * 4]) = pv;
        *reinterpret_cast<f32x4*>(&S[o + q * 4]) = sv;
    }
}

// ===== kernel 2: inter-chunk scan; H0 overwrites S in place =====
__global__ __launch_bounds__(64) void k_scan_chunks(
        const float* __restrict__ P, float* __restrict__ S_H0)
{
    int b = blockIdx.x >> 6, seg = blockIdx.x & 63;
    size_t base = (size_t)b * NC * 4096 + seg * 64 + threadIdx.x;
    float pv[8], sv[8], pn[8], sn[8];
#pragma unroll
    for (int k = 0; k < 8; k++) { pv[k] = P[base + k * 4096]; sv[k] = S_H0[base + k * 4096]; }
    float h = 0.f;
    for (int cb = 0; cb < NC / 8; cb++) {
        size_t cbase = base + (size_t)cb * 8 * 4096;
        if (cb + 1 < NC / 8) {
            size_t nbase = cbase + 8 * 4096;
#pragma unroll
            for (int k = 0; k < 8; k++) { pn[k] = P[nbase + k * 4096]; sn[k] = S_H0[nbase + k * 4096]; }
        }
        float hp[8];
#pragma unroll
        for (int k = 0; k < 8; k++) { hp[k] = h; h = fmaf(pv[k], h, sv[k]); }
#pragma unroll
        for (int k = 0; k < 8; k++) S_H0[cbase + k * 4096] = hp[k];
#pragma unroll
        for (int k = 0; k < 8; k++) { pv[k] = pn[k]; sv[k] = sn[k]; }
    }
}

// ===== kernel 3: re-scan + DFT(MFMA) + wc(MFMA) + g + inverse(MFMA) + epilogue =====
// LDS map (bytes):
//   [0, 32768)      A-tile bf16 [64m][256d] swizzled; wc bf16 [16r][1024n] after gulps
//   [32768, 66560)  hf bf16 [16r][16i][66x]
//   [66560, 68736)  g_s bf16 [16r][68k]  (k = comp*32 + x, pre-scaled by 2 for x>0)
//   [68736, 69760)  cc_b bf16 [16r][32o'] (o'>=16 zero)
//   [69760, 70784)  bc_s f32 [16t][16n]
__global__ __launch_bounds__(256, 2) void k_fused(
        const float* __restrict__ delta, const float* __restrict__ xn,
        const float* __restrict__ Bc, const float* __restrict__ Cc,
        const float* __restrict__ A_log, const float* __restrict__ H0,
        const float* __restrict__ base, float* __restrict__ out,
        const __hip_bfloat16* __restrict__ E_t, const __hip_bfloat16* __restrict__ wfrag,
        const __hip_bfloat16* __restrict__ E_inv)
{
    __shared__ __align__(16) char smem[70784];
    __bf16* hfb  = (__bf16*)(smem + 32768);
    __bf16* gsb  = (__bf16*)(smem + 66560);
    __bf16* ccb  = (__bf16*)(smem + 68736);
    float*  bc_s = (float*)(smem + 69760);

    int tid = threadIdx.x, wave = tid >> 6, lane = tid & 63;
    int blk = blockIdx.x;
    int grow0 = blk * CL;
    int d = tid;

    // ---- setup: all global loads + cc_b build ----
    bc_s[tid] = Bc[(size_t)grow0 * 16 + tid];
    {
        float ccv = Cc[(size_t)grow0 * 16 + tid];
        int r = tid >> 4, o = tid & 15;
        ccb[r * 32 + o] = (__bf16)ccv;
        ccb[r * 32 + 16 + o] = (__bf16)0.f;
    }
    float dlt[16], dxv[16];
#pragma unroll
    for (int t = 0; t < 16; t++) {
        dlt[t] = delta[(size_t)(grow0 + t) * D_ + d];
        dxv[t] = xn[(size_t)(grow0 + t) * D_ + d];
    }
    float ar[16], h[16];
    {
        size_t ho = (size_t)blk * 4096 + d * 16;
#pragma unroll
        for (int q = 0; q < 4; q++) {
            f32x4 a4 = *(const f32x4*)&A_log[d * 16 + q * 4];
            f32x4 h4 = *(const f32x4*)&H0[ho + q * 4];
#pragma unroll
            for (int k = 0; k < 4; k++) { ar[q*4+k] = -__expf(a4[k]); h[q*4+k] = h4[k]; }
        }
    }
    // DFT B-frags from E_t table (no trig)
    int xx = wave * 16 + (lane & 15);
    bf16x8 bfrag[8];
#pragma unroll
    for (int ks = 0; ks < 8; ks++)
        bfrag[ks] = *(const bf16x8*)(E_t + xx * 256 + ks * 32 + ((lane >> 4) * 8));
    int swz = (lane & 7) << 4;
    __syncthreads();

    // ---- 4 gulps: scan -> A-tile; DFT MFMA -> hf ----
#pragma unroll
    for (int g = 0; g < 4; g++) {
#pragma unroll
        for (int tl = 0; tl < 4; tl++) {
            int t = g * 4 + tl;
            float dl = dlt[t];
            float dx = dl * dxv[t];
#pragma unroll
            for (int n = 0; n < 16; n++) {
                float e = __expf(dl * ar[n]);
                h[n] = fmaf(e, h[n], dx * bc_s[t * 16 + n]);
                int m = tl * 16 + n;
                *(__bf16*)(smem + m * 512 + ((d * 2) ^ ((m & 7) << 4))) = (__bf16)h[n];
            }
        }
        __syncthreads();
        f32x4 acc[4];
#pragma unroll
        for (int mt = 0; mt < 4; mt++) { acc[mt][0]=0.f; acc[mt][1]=0.f; acc[mt][2]=0.f; acc[mt][3]=0.f; }
#pragma unroll
        for (int ks = 0; ks < 8; ks++) {
#pragma unroll
            for (int mt = 0; mt < 4; mt++) {
                int m = mt * 16 + (lane & 15);
                bf16x8 af = *(const bf16x8*)(smem + m * 512 + ((ks * 64 + ((lane >> 4) * 16)) ^ swz));
                acc[mt] = __builtin_amdgcn_mfma_f32_16x16x32_bf16(af, bfrag[ks], acc[mt], 0, 0, 0);
            }
        }
#pragma unroll
        for (int mt = 0; mt < 4; mt++) {
            int r = g * 4 + mt;
#pragma unroll
            for (int q = 0; q < 4; q++) {
                int i = (lane >> 4) * 4 + q;
                hfb[(r * 16 + i) * 66 + xx] = (__bf16)acc[mt][q];
            }
        }
        __syncthreads();
    }

    // ---- wc = Cc @ w via MFMA (M=16 r, K=32 o', N=1024), into dead A-tile region ----
    {
        bf16x8 ccf = *(const bf16x8*)((char*)ccb + (lane & 15) * 64 + ((lane >> 4) * 16));
#pragma unroll
        for (int ntl = 0; ntl < 16; ntl++) {
            int nt = wave * 16 + ntl;
            f32x4 a = {0.f, 0.f, 0.f, 0.f};
            bf16x8 wf = *(const bf16x8*)(wfrag + (nt * 64 + lane) * 8);
            a = __builtin_amdgcn_mfma_f32_16x16x32_bf16(ccf, wf, a, 0, 0, 0);
            int col = nt * 16 + (lane & 15);
#pragma unroll
            for (int q = 0; q < 4; q++) {
                int r = (lane >> 4) * 4 + q;
                *(__bf16*)(smem + r * 2048 + col * 2) = (__bf16)a[q];
            }
        }
    }
    __syncthreads();

    // ---- g[r,x] = sum_i hf[r,i,x] * wc[r,i,x] (complex); thread = (x, 2 r's) ----
    {
        int x = tid & 31, rg = tid >> 5;
#pragma unroll
        for (int r2 = 0; r2 < 2; r2++) {
            int r = rg * 2 + r2;
            float gre = 0.f, gim = 0.f;
#pragma unroll
            for (int i = 0; i < 16; i++) {
                float hr = (float)hfb[(r * 16 + i) * 66 + x];
                float hi = (float)hfb[(r * 16 + i) * 66 + 32 + x];
                float wr = (float)*(__bf16*)(smem + r * 2048 + (i * 64 + x) * 2);
                float wi = (float)*(__bf16*)(smem + r * 2048 + (i * 64 + 32 + x) * 2);
                gre = fmaf(hr, wr, gre); gre = fmaf(-hi, wi, gre);
                gim = fmaf(hr, wi, gim); gim = fmaf(hi, wr, gim);
            }
            float sc = x ? 2.f : 1.f;
            gsb[r * 68 + x]      = (__bf16)(gre * sc);
            gsb[r * 68 + 32 + x] = (__bf16)(gim * sc);
        }
    }
    __syncthreads();

    // ---- inverse DFT via MFMA (M=16 r, K=64, N=256 d') + epilogue ----
    {
        bf16x8 ga0 = *(const bf16x8*)((char*)gsb + (lane & 15) * 136 + ((lane >> 4) * 16));
        bf16x8 ga1 = *(const bf16x8*)((char*)gsb + (lane & 15) * 136 + 64 + ((lane >> 4) * 16));
#pragma unroll
        for (int ntl = 0; ntl < 4; ntl++) {
            int nt = wave * 4 + ntl;
            f32x4 a = {0.f, 0.f, 0.f, 0.f};
            a = __builtin_amdgcn_mfma_f32_16x16x32_bf16(
                    ga0, *(const bf16x8*)(E_inv + ((nt * 2 + 0) * 64 + lane) * 8), a, 0, 0, 0);
            a = __builtin_amdgcn_mfma_f32_16x16x32_bf16(
                    ga1, *(const bf16x8*)(E_inv + ((nt * 2 + 1) * 64 + lane) * 8), a, 0, 0, 0);
            int dcol = nt * 16 + (lane & 15);
#pragma unroll
            for (int q = 0; q < 4; q++) {
                int r = (lane >> 4) * 4 + q;
                size_t go = (size_t)(grow0 + r) * D_ + dcol;
                out[go] = base[go] + a[q] * (1.f / 256.f);
            }
        }
    }
}

// ===== launch =====
extern "C" void kernel_launch(void* const* d_in, const int* in_sizes, int n_in,
                              void* d_out, int out_size, void* d_ws, size_t ws_size,
                              hipStream_t stream)
{
    const float* x       = (const float*)d_in[0];
    const float* ln_g    = (const float*)d_in[1];
    const float* ln_b    = (const float*)d_in[2];
    const float* W_xproj = (const float*)d_in[3];
    const float* W_dt    = (const float*)d_in[4];
    const float* b_dt    = (const float*)d_in[5];
    const float* A_log   = (const float*)d_in[6];
    const float* D_param = (const float*)d_in[7];
    const float* w_re    = (const float*)d_in[8];
    const float* w_im    = (const float*)d_in[9];

    float* ws    = (float*)d_ws;
    float* xn    = ws;                         // 2M floats
    float* delta = xn + 2097152;               // 2M
    float* base  = delta + 2097152;            // 2M
    float* Bc    = base + 2097152;             // 131072
    float* Cc    = Bc + 131072;                // 131072
    float* S_H0  = Cc + 131072;                // 2M (S, then H0 in place)
    float* P     = S_H0 + 2097152;             // 2M
    __hip_bfloat16* tab = (__hip_bfloat16*)(P + 2097152);
    __hip_bfloat16* E_t   = tab;               // 16384 bf16
    __hip_bfloat16* Wfrag = tab + 16384;       // 16384
    __hip_bfloat16* wfrag = tab + 32768;       // 32768
    __hip_bfloat16* E_inv = tab + 65536;       // 16384
    float* out = (float*)d_out;

    hipLaunchKernelGGL(k_prep,        dim3(320),   dim3(256), 0, stream,
                       W_xproj, w_re, w_im, E_t, Wfrag, wfrag, E_inv);
    hipLaunchKernelGGL(k_lnscan,      dim3(B_*NC), dim3(256), 0, stream,
                       x, ln_g, ln_b, W_dt, b_dt, D_param, A_log, Wfrag,
                       xn, delta, base, Bc, Cc, P, S_H0);
    hipLaunchKernelGGL(k_scan_chunks, dim3(256),   dim3(64),  0, stream, P, S_H0);
    hipLaunchKernelGGL(k_fused,       dim3(B_*NC), dim3(256), 0, stream,
                       delta, xn, Bc, Cc, A_log, S_H0, base, out, E_t, wfrag, E_inv);
}

// Round 7
// 56.244 us; speedup vs baseline: 7.3068x; 1.1295x over previous
//
#include <hip/hip_runtime.h>
#include <hip/hip_bf16.h>

// Problem constants
#define B_   4
#define L_   2048
#define D_   256
#define NC   128
#define CL   16
#define ANG  0.02454369260617025967f   // 2*pi/256

typedef __bf16 bf16x8 __attribute__((ext_vector_type(8)));
typedef float  f32x4  __attribute__((ext_vector_type(4)));

// ===== kernel 0: build bf16 fragment tables (per-call, cheap) =====
__global__ __launch_bounds__(256) void k_prep(
        const float* __restrict__ W_xproj, const float* __restrict__ w_re, const float* __restrict__ w_im,
        __hip_bfloat16* __restrict__ E_t, __hip_bfloat16* __restrict__ Wfrag,
        __hip_bfloat16* __restrict__ wfrag, __hip_bfloat16* __restrict__ E_inv)
{
    int idx = blockIdx.x * 256 + threadIdx.x;
    if (idx < 16384) {
        int x = idx >> 8, d = idx & 255;
        float v = (x < 32) ? __cosf(ANG * (float)((x * d) & 255))
                           : -__sinf(ANG * (float)(((x - 32) * d) & 255));
        E_t[idx] = __float2bfloat16(v);
    } else if (idx < 32768) {
        int f = idx - 16384;
        int ks = f >> 11, t = (f >> 3) & 255, j = f & 7;
        int jcol = (t >> 6) * 16 + (t & 15);
        int dd = ks * 32 + ((t >> 4) & 3) * 8 + j;
        float v = (jcol < 48) ? W_xproj[jcol * 256 + dd] : 0.f;
        Wfrag[f] = __float2bfloat16(v);
    } else if (idx < 65536) {
        int f = idx - 32768;
        int nt = f >> 9, l = (f >> 3) & 63, j = f & 7;
        int n = nt * 16 + (l & 15);
        int o = ((l >> 4) & 3) * 8 + j;          // k = o' 0..31
        float v = 0.f;
        if (o < 16) {
            int i = n >> 6, comp = (n >> 5) & 1, x = n & 31;
            v = comp ? w_im[(i * 16 + o) * 32 + x] : w_re[(i * 16 + o) * 32 + x];
        }
        wfrag[f] = __float2bfloat16(v);
    } else if (idx < 81920) {
        int f = idx - 65536;
        int nt = f >> 10, ks = (f >> 9) & 1, l = (f >> 3) & 63, j = f & 7;
        int row = ks * 32 + ((l >> 4) & 3) * 8 + j;
        int col = nt * 16 + (l & 15);
        float v = (row < 32) ? __cosf(ANG * (float)((row * col) & 255))
                             : -__sinf(ANG * (float)(((row - 32) * col) & 255));
        E_inv[f] = __float2bfloat16(v);
    }
}

// ===== kernel 1: LN + proj(MFMA) + delta + local scan (per 16-row chunk) =====
__global__ __launch_bounds__(256) void k_lnscan(
        const float* __restrict__ x, const float* __restrict__ ln_g, const float* __restrict__ ln_b,
        const float* __restrict__ W_dt, const float* __restrict__ b_dt,
        const float* __restrict__ D_param, const float* __restrict__ A_log,
        const __hip_bfloat16* __restrict__ Wfrag,
        unsigned int* __restrict__ dxn, float* __restrict__ base_o,
        float* __restrict__ Bc_o, float* __restrict__ Cc_o,
        float* __restrict__ P, float* __restrict__ S)
{
    __shared__ __align__(16) float xn_s[16 * 260];   // f32, stride 260 -> conflict-free
    __shared__ __align__(16) __bf16 xnb[16 * 256];   // bf16 A-tile [m][d], XOR-swizzled
    __shared__ float dbc_s[16 * 52];
    int tid = threadIdx.x, wave = tid >> 6, lane = tid & 63;
    int blk = blockIdx.x;
    int grow0 = blk * CL;
    char* xnb_c = (char*)xnb;

    // --- Phase A: LayerNorm, 4 rows per wave ---
#pragma unroll
    for (int rr = 0; rr < 4; rr++) {
        int r = wave * 4 + rr;
        const float* xr = x + (size_t)(grow0 + r) * D_;
        float v[4];
#pragma unroll
        for (int q = 0; q < 4; q++) v[q] = xr[lane + q * 64];
        float sum = v[0] + v[1] + v[2] + v[3];
        float sq  = v[0]*v[0] + v[1]*v[1] + v[2]*v[2] + v[3]*v[3];
#pragma unroll
        for (int off = 32; off; off >>= 1) { sum += __shfl_xor(sum, off); sq += __shfl_xor(sq, off); }
        float mu = sum * (1.f / D_);
        float rstd = rsqrtf(sq * (1.f / D_) - mu * mu + 1e-5f);
#pragma unroll
        for (int q = 0; q < 4; q++) {
            int d = lane + q * 64;
            float xv = (v[q] - mu) * rstd * ln_g[d] + ln_b[d];
            xn_s[r * 260 + d] = xv;
            *(__bf16*)(xnb_c + r * 512 + ((d * 2) ^ ((r & 7) << 4))) = (__bf16)xv;
            base_o[(size_t)(grow0 + r) * D_ + d] = v[q] + D_param[d] * xv;
        }
    }
    __syncthreads();

    // --- Phase B: dbc = xn @ W_xproj^T via MFMA (M=16 rows, N=64 j, K=256) ---
    {
        int mrow = lane & 15;
        f32x4 acc = {0.f, 0.f, 0.f, 0.f};
#pragma unroll
        for (int ks = 0; ks < 8; ks++) {
            bf16x8 af = *(const bf16x8*)(xnb_c + mrow * 512 +
                          ((ks * 64 + ((lane >> 4) * 16)) ^ ((mrow & 7) << 4)));
            bf16x8 bf = *(const bf16x8*)(Wfrag + (ks * 256 + tid) * 8);
            acc = __builtin_amdgcn_mfma_f32_16x16x32_bf16(af, bf, acc, 0, 0, 0);
        }
        int j = wave * 16 + (lane & 15);
#pragma unroll
        for (int q = 0; q < 4; q++) {
            int r = (lane >> 4) * 4 + q;
            if (j < 48) dbc_s[r * 52 + j] = acc[q];
            if (j >= 32 && j < 48)      Cc_o[(size_t)(grow0 + r) * 16 + j - 32] = acc[q];
            else if (j >= 16 && j < 32) Bc_o[(size_t)(grow0 + r) * 16 + j - 16] = acc[q];
        }
    }
    __syncthreads();

    // --- Phase C: delta = softplus(dbc[:16] . W_dt[d] + b_dt[d]); pack dxn ---
    int d = tid;
    float wdt[16];
#pragma unroll
    for (int q = 0; q < 4; q++) {
        f32x4 w4 = *(const f32x4*)&W_dt[d * 16 + q * 4];
#pragma unroll
        for (int k = 0; k < 4; k++) wdt[q * 4 + k] = w4[k];
    }
    float bd = b_dt[d];
    float dlt_r[16];
#pragma unroll
    for (int r = 0; r < 16; r++) {
        float din = bd;
#pragma unroll
        for (int k = 0; k < 16; k++) din = fmaf(dbc_s[r * 52 + k], wdt[k], din);
        din = (din > 15.f) ? din : log1pf(__expf(din));
        dlt_r[r] = din;
        union { __bf16 h2[2]; unsigned int u; } pk;
        pk.h2[0] = (__bf16)din;
        pk.h2[1] = (__bf16)xn_s[r * 260 + d];
        dxn[(size_t)(grow0 + r) * D_ + d] = pk.u;
    }

    // --- Phase D: local scan over 16 timesteps (uniform-A fast path) ---
    float ar[16];
#pragma unroll
    for (int q = 0; q < 4; q++) {
        f32x4 a4 = *(const f32x4*)&A_log[d * 16 + q * 4];
#pragma unroll
        for (int k = 0; k < 4; k++) ar[q * 4 + k] = -__expf(a4[k]);
    }
    bool uni = true;
#pragma unroll
    for (int n = 1; n < 16; n++) uni = uni && (ar[n] == ar[0]);
    float s[16], dsum = 0.f;
#pragma unroll
    for (int n = 0; n < 16; n++) s[n] = 0.f;
    if (uni) {
        float ar0 = ar[0];
#pragma unroll
        for (int t = 0; t < CL; t++) {
            float dl = dlt_r[t];
            float dx = dl * xn_s[t * 260 + d];
            dsum += dl;
            float e = __expf(dl * ar0);
#pragma unroll
            for (int n = 0; n < 16; n++)
                s[n] = fmaf(e, s[n], dx * dbc_s[t * 52 + 16 + n]);
        }
    } else {
#pragma unroll
        for (int t = 0; t < CL; t++) {
            float dl = dlt_r[t];
            float dx = dl * xn_s[t * 260 + d];
            dsum += dl;
#pragma unroll
            for (int n = 0; n < 16; n++) {
                float e = __expf(dl * ar[n]);
                s[n] = fmaf(e, s[n], dx * dbc_s[t * 52 + 16 + n]);
            }
        }
    }
    size_t o = (size_t)blk * 4096 + d * 16;
    if (uni) {
        float p0 = __expf(ar[0] * dsum);
#pragma unroll
        for (int q = 0; q < 4; q++) {
            f32x4 pv, sv;
#pragma unroll
            for (int k = 0; k < 4; k++) { pv[k] = p0; sv[k] = s[q*4+k]; }
            *reinterpret_cast<f32x4*>(&P[o + q * 4]) = pv;
            *reinterpret_cast<f32x4*>(&S[o + q * 4]) = sv;
        }
    } else {
#pragma unroll
        for (int q = 0; q < 4; q++) {
            f32x4 pv, sv;
#pragma unroll
            for (int k = 0; k < 4; k++) { pv[k] = __expf(ar[q*4+k] * dsum); sv[k] = s[q*4+k]; }
            *reinterpret_cast<f32x4*>(&P[o + q * 4]) = pv;
            *reinterpret_cast<f32x4*>(&S[o + q * 4]) = sv;
        }
    }
}

// ===== kernel 2: inter-chunk scan, 8-way parallel; H0 overwrites S in place =====
__global__ __launch_bounds__(256) void k_scan_par(
        const float* __restrict__ P, float* __restrict__ S_H0)
{
    __shared__ float gPS[512];
    int tid = threadIdx.x;
    int g2 = tid >> 5, cl2 = tid & 31;
    int ch = blockIdx.x * 32 + cl2;               // 512*32 = 16384 channels
    int b2 = ch >> 12, dn2 = ch & 4095;
    size_t cb = ((size_t)b2 * NC + g2 * 16) * 4096 + dn2;
    float pv[16], sv[16];
#pragma unroll
    for (int c = 0; c < 16; c++) {
        pv[c] = P[cb + (size_t)c * 4096];
        sv[c] = S_H0[cb + (size_t)c * 4096];
    }
    float pA = 1.f, sA = 0.f;
#pragma unroll
    for (int c = 0; c < 16; c++) { sA = fmaf(pv[c], sA, sv[c]); pA *= pv[c]; }
    gPS[(g2 * 32 + cl2) * 2 - (g2 * 32 + cl2)] = 0.f; // (dummy to keep layout simple? no)
    gPS[(g2 * 32 + cl2)] = pA;                    // [0,256): pA
    __syncthreads();
    __shared__ float gS2[256];
    gS2[g2 * 32 + cl2] = sA;
    __syncthreads();
    float h = 0.f;
    for (int gg = 0; gg < g2; gg++)
        h = fmaf(gPS[gg * 32 + cl2], h, gS2[gg * 32 + cl2]);
#pragma unroll
    for (int c = 0; c < 16; c++) {
        S_H0[cb + (size_t)c * 4096] = h;          // H0 for chunk (g2*16+c), in place
        h = fmaf(pv[c], h, sv[c]);
    }
}

// ===== kernel 3: re-scan + DFT(MFMA) + wc(MFMA) + g + inverse(MFMA) + epilogue =====
// LDS map (bytes):
//   [0, 32768)      A-tile bf16 [64m][256d] swizzled; wc bf16 [16r][1024n] after gulps
//   [32768, 66560)  hf bf16 [16r][16i][66x]
//   [66560, 68736)  g_s bf16 [16r][68k]
//   [68736, 69760)  cc_b bf16 [16r][32o'] (o'>=16 zero)
//   [69760, 70784)  bc_s f32 [16t][16n]
__global__ __launch_bounds__(256, 2) void k_fused(
        const unsigned int* __restrict__ dxn,
        const float* __restrict__ Bc, const float* __restrict__ Cc,
        const float* __restrict__ A_log, const float* __restrict__ H0,
        const float* __restrict__ base, float* __restrict__ out,
        const __hip_bfloat16* __restrict__ E_t, const __hip_bfloat16* __restrict__ wfrag,
        const __hip_bfloat16* __restrict__ E_inv)
{
    __shared__ __align__(16) char smem[70784];
    __bf16* hfb  = (__bf16*)(smem + 32768);
    __bf16* gsb  = (__bf16*)(smem + 66560);
    __bf16* ccb  = (__bf16*)(smem + 68736);
    float*  bc_s = (float*)(smem + 69760);

    int tid = threadIdx.x, wave = tid >> 6, lane = tid & 63;
    int blk = blockIdx.x;
    int grow0 = blk * CL;
    int d = tid;

    // ---- setup: all global loads + cc_b build ----
    bc_s[tid] = Bc[(size_t)grow0 * 16 + tid];
    {
        float ccv = Cc[(size_t)grow0 * 16 + tid];
        int r = tid >> 4, o = tid & 15;
        ccb[r * 32 + o] = (__bf16)ccv;
        ccb[r * 32 + 16 + o] = (__bf16)0.f;
    }
    float dlt[16], dxv[16];
#pragma unroll
    for (int t = 0; t < 16; t++) {
        unsigned int v = dxn[(size_t)(grow0 + t) * D_ + d];
        dlt[t] = __uint_as_float(v << 16);
        dxv[t] = __uint_as_float(v & 0xffff0000u);
    }
    float ar[16], h[16];
    {
        size_t ho = (size_t)blk * 4096 + d * 16;
#pragma unroll
        for (int q = 0; q < 4; q++) {
            f32x4 a4 = *(const f32x4*)&A_log[d * 16 + q * 4];
            f32x4 h4 = *(const f32x4*)&H0[ho + q * 4];
#pragma unroll
            for (int k = 0; k < 4; k++) { ar[q*4+k] = -__expf(a4[k]); h[q*4+k] = h4[k]; }
        }
    }
    bool uni = true;
#pragma unroll
    for (int n = 1; n < 16; n++) uni = uni && (ar[n] == ar[0]);
    float ar0 = ar[0];

    // DFT B-frags from E_t table (no trig)
    int xx = wave * 16 + (lane & 15);
    bf16x8 bfrag[8];
#pragma unroll
    for (int ks = 0; ks < 8; ks++)
        bfrag[ks] = *(const bf16x8*)(E_t + xx * 256 + ks * 32 + ((lane >> 4) * 8));
    int swz = (lane & 7) << 4;
    __syncthreads();

    // ---- 4 gulps: scan -> A-tile; DFT MFMA -> hf ----
#pragma unroll
    for (int g = 0; g < 4; g++) {
        if (uni) {
#pragma unroll
            for (int tl = 0; tl < 4; tl++) {
                int t = g * 4 + tl;
                float dl = dlt[t];
                float dx = dl * dxv[t];
                float e = __expf(dl * ar0);
#pragma unroll
                for (int n = 0; n < 16; n++) {
                    h[n] = fmaf(e, h[n], dx * bc_s[t * 16 + n]);
                    int m = tl * 16 + n;
                    *(__bf16*)(smem + m * 512 + ((d * 2) ^ ((m & 7) << 4))) = (__bf16)h[n];
                }
            }
        } else {
#pragma unroll
            for (int tl = 0; tl < 4; tl++) {
                int t = g * 4 + tl;
                float dl = dlt[t];
                float dx = dl * dxv[t];
#pragma unroll
                for (int n = 0; n < 16; n++) {
                    float e = __expf(dl * ar[n]);
                    h[n] = fmaf(e, h[n], dx * bc_s[t * 16 + n]);
                    int m = tl * 16 + n;
                    *(__bf16*)(smem + m * 512 + ((d * 2) ^ ((m & 7) << 4))) = (__bf16)h[n];
                }
            }
        }
        __syncthreads();
        f32x4 acc[4];
#pragma unroll
        for (int mt = 0; mt < 4; mt++) { acc[mt][0]=0.f; acc[mt][1]=0.f; acc[mt][2]=0.f; acc[mt][3]=0.f; }
#pragma unroll
        for (int ks = 0; ks < 8; ks++) {
#pragma unroll
            for (int mt = 0; mt < 4; mt++) {
                int m = mt * 16 + (lane & 15);
                bf16x8 af = *(const bf16x8*)(smem + m * 512 + ((ks * 64 + ((lane >> 4) * 16)) ^ swz));
                acc[mt] = __builtin_amdgcn_mfma_f32_16x16x32_bf16(af, bfrag[ks], acc[mt], 0, 0, 0);
            }
        }
#pragma unroll
        for (int mt = 0; mt < 4; mt++) {
            int r = g * 4 + mt;
#pragma unroll
            for (int q = 0; q < 4; q++) {
                int i = (lane >> 4) * 4 + q;
                hfb[(r * 16 + i) * 66 + xx] = (__bf16)acc[mt][q];
            }
        }
        __syncthreads();
    }

    // ---- wc = Cc @ w via MFMA (M=16 r, K=32 o', N=1024), into dead A-tile region ----
    {
        bf16x8 ccf = *(const bf16x8*)((char*)ccb + (lane & 15) * 64 + ((lane >> 4) * 16));
#pragma unroll
        for (int ntl = 0; ntl < 16; ntl++) {
            int nt = wave * 16 + ntl;
            f32x4 a = {0.f, 0.f, 0.f, 0.f};
            bf16x8 wf = *(const bf16x8*)(wfrag + (nt * 64 + lane) * 8);
            a = __builtin_amdgcn_mfma_f32_16x16x32_bf16(ccf, wf, a, 0, 0, 0);
            int col = nt * 16 + (lane & 15);
#pragma unroll
            for (int q = 0; q < 4; q++) {
                int r = (lane >> 4) * 4 + q;
                *(__bf16*)(smem + r * 2048 + col * 2) = (__bf16)a[q];
            }
        }
    }
    __syncthreads();

    // ---- g[r,x] = sum_i hf[r,i,x] * wc[r,i,x] (complex); thread = (x, 2 r's) ----
    {
        int xs = tid & 31, rg = tid >> 5;
#pragma unroll
        for (int r2 = 0; r2 < 2; r2++) {
            int r = rg * 2 + r2;
            float gre = 0.f, gim = 0.f;
#pragma unroll
            for (int i = 0; i < 16; i++) {
                float hr = (float)hfb[(r * 16 + i) * 66 + xs];
                float hi = (float)hfb[(r * 16 + i) * 66 + 32 + xs];
                float wr = (float)*(__bf16*)(smem + r * 2048 + (i * 64 + xs) * 2);
                float wi = (float)*(__bf16*)(smem + r * 2048 + (i * 64 + 32 + xs) * 2);
                gre = fmaf(hr, wr, gre); gre = fmaf(-hi, wi, gre);
                gim = fmaf(hr, wi, gim); gim = fmaf(hi, wr, gim);
            }
            float sc = xs ? 2.f : 1.f;
            gsb[r * 68 + xs]      = (__bf16)(gre * sc);
            gsb[r * 68 + 32 + xs] = (__bf16)(gim * sc);
        }
    }
    __syncthreads();

    // ---- inverse DFT via MFMA (M=16 r, K=64, N=256 d') + epilogue ----
    {
        bf16x8 ga0 = *(const bf16x8*)((char*)gsb + (lane & 15) * 136 + ((lane >> 4) * 16));
        bf16x8 ga1 = *(const bf16x8*)((char*)gsb + (lane & 15) * 136 + 64 + ((lane >> 4) * 16));
#pragma unroll
        for (int ntl = 0; ntl < 4; ntl++) {
            int nt = wave * 4 + ntl;
            f32x4 a = {0.f, 0.f, 0.f, 0.f};
            a = __builtin_amdgcn_mfma_f32_16x16x32_bf16(
                    ga0, *(const bf16x8*)(E_inv + ((nt * 2 + 0) * 64 + lane) * 8), a, 0, 0, 0);
            a = __builtin_amdgcn_mfma_f32_16x16x32_bf16(
                    ga1, *(const bf16x8*)(E_inv + ((nt * 2 + 1) * 64 + lane) * 8), a, 0, 0, 0);
            int dcol = nt * 16 + (lane & 15);
#pragma unroll
            for (int q = 0; q < 4; q++) {
                int r = (lane >> 4) * 4 + q;
                size_t go = (size_t)(grow0 + r) * D_ + dcol;
                out[go] = base[go] + a[q] * (1.f / 256.f);
            }
        }
    }
}

// ===== launch =====
extern "C" void kernel_launch(void* const* d_in, const int* in_sizes, int n_in,
                              void* d_out, int out_size, void* d_ws, size_t ws_size,
                              hipStream_t stream)
{
    const float* x       = (const float*)d_in[0];
    const float* ln_g    = (const float*)d_in[1];
    const float* ln_b    = (const float*)d_in[2];
    const float* W_xproj = (const float*)d_in[3];
    const float* W_dt    = (const float*)d_in[4];
    const float* b_dt    = (const float*)d_in[5];
    const float* A_log   = (const float*)d_in[6];
    const float* D_param = (const float*)d_in[7];
    const float* w_re    = (const float*)d_in[8];
    const float* w_im    = (const float*)d_in[9];

    float* ws    = (float*)d_ws;
    float* base  = ws;                               // 2M floats
    float* S_H0  = base + 2097152;                   // 2M (S, then H0 in place)
    float* P     = S_H0 + 2097152;                   // 2M
    unsigned int* dxn = (unsigned int*)(P + 2097152);// 2M u32 (bf16 dlt | bf16 xn)
    float* Bc    = (float*)(dxn + 2097152);          // 131072
    float* Cc    = Bc + 131072;                      // 131072
    __hip_bfloat16* tab = (__hip_bfloat16*)(Cc + 131072);
    __hip_bfloat16* E_t   = tab;                     // 16384 bf16
    __hip_bfloat16* Wfrag = tab + 16384;             // 16384
    __hip_bfloat16* wfrag = tab + 32768;             // 32768
    __hip_bfloat16* E_inv = tab + 65536;             // 16384
    float* out = (float*)d_out;

    hipLaunchKernelGGL(k_prep, dim3(320), dim3(256), 0, stream,
                       W_xproj, w_re, w_im, E_t, Wfrag, wfrag, E_inv);
    hipLaunchKernelGGL(k_lnscan, dim3(B_*NC), dim3(256), 0, stream,
                       x, ln_g, ln_b, W_dt, b_dt, D_param, A_log, Wfrag,
                       dxn, base, Bc, Cc, P, S_H0);
    hipLaunchKernelGGL(k_scan_par, dim3(B_*NC), dim3(256), 0, stream, P, S_H0);
    hipLaunchKernelGGL(k_fused, dim3(B_*NC), dim3(256), 0, stream,
                       dxn, Bc, Cc, A_log, S_H0, base, out, E_t, wfrag, E_inv);
}

// Round 8
// 54.310 us; speedup vs baseline: 7.5670x; 1.0356x over previous
//
#include <hip/hip_runtime.h>
#include <hip/hip_bf16.h>

// Problem constants
#define B_   4
#define L_   2048
#define D_   256
#define NC   128
#define CL   16
#define ANG  0.02454369260617025967f   // 2*pi/256

typedef __bf16 bf16x8 __attribute__((ext_vector_type(8)));
typedef __bf16 bf16x4 __attribute__((ext_vector_type(4)));
typedef float  f32x4  __attribute__((ext_vector_type(4)));

// ===== kernel 0: build bf16 fragment tables (per-call, cheap) =====
// E_t   [64 x][256 d]       : x<32 -> cos(ANG*x*d), else -sin(ANG*(x-32)*d)
// Wfrag [8 ks][256 tid][8 j]: B-frags for dbc MFMA (B[k=d][n=j] = W_xproj^T, j>=48 -> 0)
// wfrag [64 nt][64 l][8 j]  : B-frags for wc MFMA; n = comp*512 + x*16 + i
// E_inv [16 nt][2 ks][64 l][8 j]: B-frags for inverse MFMA
__global__ __launch_bounds__(256) void k_prep(
        const float* __restrict__ W_xproj, const float* __restrict__ w_re, const float* __restrict__ w_im,
        __hip_bfloat16* __restrict__ E_t, __hip_bfloat16* __restrict__ Wfrag,
        __hip_bfloat16* __restrict__ wfrag, __hip_bfloat16* __restrict__ E_inv)
{
    int idx = blockIdx.x * 256 + threadIdx.x;
    if (idx < 16384) {
        int x = idx >> 8, d = idx & 255;
        float v = (x < 32) ? __cosf(ANG * (float)((x * d) & 255))
                           : -__sinf(ANG * (float)(((x - 32) * d) & 255));
        E_t[idx] = __float2bfloat16(v);
    } else if (idx < 32768) {
        int f = idx - 16384;
        int ks = f >> 11, t = (f >> 3) & 255, j = f & 7;
        int jcol = (t >> 6) * 16 + (t & 15);
        int dd = ks * 32 + ((t >> 4) & 3) * 8 + j;
        float v = (jcol < 48) ? W_xproj[jcol * 256 + dd] : 0.f;
        Wfrag[f] = __float2bfloat16(v);
    } else if (idx < 65536) {
        int f = idx - 32768;
        int nt = f >> 9, l = (f >> 3) & 63, j = f & 7;
        int n = nt * 16 + (l & 15);
        int o = ((l >> 4) & 3) * 8 + j;          // k = o' 0..31
        float v = 0.f;
        if (o < 16) {
            int comp = n >> 9, x = (n >> 4) & 31, i = n & 15;
            v = comp ? w_im[(i * 16 + o) * 32 + x] : w_re[(i * 16 + o) * 32 + x];
        }
        wfrag[f] = __float2bfloat16(v);
    } else if (idx < 81920) {
        int f = idx - 65536;
        int nt = f >> 10, ks = (f >> 9) & 1, l = (f >> 3) & 63, j = f & 7;
        int row = ks * 32 + ((l >> 4) & 3) * 8 + j;
        int col = nt * 16 + (l & 15);
        float v = (row < 32) ? __cosf(ANG * (float)((row * col) & 255))
                             : -__sinf(ANG * (float)(((row - 32) * col) & 255));
        E_inv[f] = __float2bfloat16(v);
    }
}

// ===== kernel 1: LN + proj(MFMA) + delta + local scan (per 16-row chunk) =====
__global__ __launch_bounds__(256) void k_lnscan(
        const float* __restrict__ x, const float* __restrict__ ln_g, const float* __restrict__ ln_b,
        const float* __restrict__ W_dt, const float* __restrict__ b_dt,
        const float* __restrict__ A_log,
        const __hip_bfloat16* __restrict__ Wfrag,
        unsigned int* __restrict__ dxn,
        float* __restrict__ Bc_o, float* __restrict__ Cc_o,
        float* __restrict__ dsum_o, float* __restrict__ S)
{
    __shared__ __align__(16) float xn_s[16 * 260];   // stride 260 -> conflict-free
    __shared__ __align__(16) __bf16 xnb[16 * 256];   // bf16 A-tile [m][d], XOR-swizzled
    __shared__ float dbc_s[16 * 52];
    int tid = threadIdx.x, wave = tid >> 6, lane = tid & 63;
    int blk = blockIdx.x;
    int grow0 = blk * CL;
    char* xnb_c = (char*)xnb;

    // --- Phase A: LayerNorm, 4 rows per wave ---
#pragma unroll
    for (int rr = 0; rr < 4; rr++) {
        int r = wave * 4 + rr;
        const float* xr = x + (size_t)(grow0 + r) * D_;
        float v[4];
#pragma unroll
        for (int q = 0; q < 4; q++) v[q] = xr[lane + q * 64];
        float sum = v[0] + v[1] + v[2] + v[3];
        float sq  = v[0]*v[0] + v[1]*v[1] + v[2]*v[2] + v[3]*v[3];
#pragma unroll
        for (int off = 32; off; off >>= 1) { sum += __shfl_xor(sum, off); sq += __shfl_xor(sq, off); }
        float mu = sum * (1.f / D_);
        float rstd = rsqrtf(sq * (1.f / D_) - mu * mu + 1e-5f);
#pragma unroll
        for (int q = 0; q < 4; q++) {
            int d = lane + q * 64;
            float xv = (v[q] - mu) * rstd * ln_g[d] + ln_b[d];
            xn_s[r * 260 + d] = xv;
            *(__bf16*)(xnb_c + r * 512 + ((d * 2) ^ ((r & 7) << 4))) = (__bf16)xv;
        }
    }
    __syncthreads();

    // --- Phase B: dbc = xn @ W_xproj^T via MFMA (M=16 rows, N=64 j, K=256) ---
    {
        int mrow = lane & 15;
        f32x4 acc = {0.f, 0.f, 0.f, 0.f};
#pragma unroll
        for (int ks = 0; ks < 8; ks++) {
            bf16x8 af = *(const bf16x8*)(xnb_c + mrow * 512 +
                          ((ks * 64 + ((lane >> 4) * 16)) ^ ((mrow & 7) << 4)));
            bf16x8 bf = *(const bf16x8*)(Wfrag + (ks * 256 + tid) * 8);
            acc = __builtin_amdgcn_mfma_f32_16x16x32_bf16(af, bf, acc, 0, 0, 0);
        }
        int j = wave * 16 + (lane & 15);
#pragma unroll
        for (int q = 0; q < 4; q++) {
            int r = (lane >> 4) * 4 + q;
            if (j < 48) dbc_s[r * 52 + j] = acc[q];
            if (j >= 32 && j < 48)      Cc_o[(size_t)(grow0 + r) * 16 + j - 32] = acc[q];
            else if (j >= 16 && j < 32) Bc_o[(size_t)(grow0 + r) * 16 + j - 16] = acc[q];
        }
    }
    __syncthreads();

    // --- Phase C: delta = softplus(dbc[:16] . W_dt[d] + b_dt[d]); pack dxn ---
    int d = tid;
    float wdt[16];
#pragma unroll
    for (int q = 0; q < 4; q++) {
        f32x4 w4 = *(const f32x4*)&W_dt[d * 16 + q * 4];
#pragma unroll
        for (int k = 0; k < 4; k++) wdt[q * 4 + k] = w4[k];
    }
    float bd = b_dt[d];
    float dlt_r[16];
#pragma unroll
    for (int r = 0; r < 16; r++) {
        float din = bd;
#pragma unroll
        for (int k = 0; k < 16; k++) din = fmaf(dbc_s[r * 52 + k], wdt[k], din);
        din = (din > 15.f) ? din : log1pf(__expf(din));
        dlt_r[r] = din;
        union { __bf16 h2[2]; unsigned int u; } pk;
        pk.h2[0] = (__bf16)din;
        pk.h2[1] = (__bf16)xn_s[r * 260 + d];
        dxn[(size_t)(grow0 + r) * D_ + d] = pk.u;
    }

    // --- Phase D: local scan over 16 timesteps (uniform-A fast path) ---
    float ar[16];
#pragma unroll
    for (int q = 0; q < 4; q++) {
        f32x4 a4 = *(const f32x4*)&A_log[d * 16 + q * 4];
#pragma unroll
        for (int k = 0; k < 4; k++) ar[q * 4 + k] = -__expf(a4[k]);
    }
    bool uni = true;
#pragma unroll
    for (int n = 1; n < 16; n++) uni = uni && (ar[n] == ar[0]);
    float s[16], dsum = 0.f;
#pragma unroll
    for (int n = 0; n < 16; n++) s[n] = 0.f;
    if (uni) {
        float ar0 = ar[0];
#pragma unroll
        for (int t = 0; t < CL; t++) {
            float dl = dlt_r[t];
            float dx = dl * xn_s[t * 260 + d];
            dsum += dl;
            float e = __expf(dl * ar0);
#pragma unroll
            for (int n = 0; n < 16; n++)
                s[n] = fmaf(e, s[n], dx * dbc_s[t * 52 + 16 + n]);
        }
    } else {
#pragma unroll
        for (int t = 0; t < CL; t++) {
            float dl = dlt_r[t];
            float dx = dl * xn_s[t * 260 + d];
            dsum += dl;
#pragma unroll
            for (int n = 0; n < 16; n++) {
                float e = __expf(dl * ar[n]);
                s[n] = fmaf(e, s[n], dx * dbc_s[t * 52 + 16 + n]);
            }
        }
    }
    dsum_o[(size_t)blk * 256 + d] = dsum;
    size_t o = (size_t)blk * 4096 + d * 16;
#pragma unroll
    for (int q = 0; q < 4; q++) {
        f32x4 sv;
#pragma unroll
        for (int k = 0; k < 4; k++) sv[k] = s[q*4+k];
        *reinterpret_cast<f32x4*>(&S[o + q * 4]) = sv;
    }
}

// ===== kernel 2: inter-chunk scan, 8-way parallel; pv = exp(ar*dsum) =====
__global__ __launch_bounds__(256) void k_scan_par(
        const float* __restrict__ A_log, const float* __restrict__ dsum,
        float* __restrict__ S_H0)
{
    __shared__ float gP[256];
    __shared__ float gS[256];
    int tid = threadIdx.x;
    int g2 = tid >> 5, cl2 = tid & 31;
    int ch = blockIdx.x * 32 + cl2;               // 512*32 = 16384 channels
    int b2 = ch >> 12, dn2 = ch & 4095;
    int dd = dn2 >> 4;
    float arv = -__expf(A_log[dn2]);
    size_t cb = ((size_t)b2 * NC + g2 * 16) * 4096 + dn2;
    size_t db = ((size_t)b2 * NC + g2 * 16) * 256 + dd;
    float pv[16], sv[16];
#pragma unroll
    for (int c = 0; c < 16; c++) {
        pv[c] = __expf(arv * dsum[db + (size_t)c * 256]);
        sv[c] = S_H0[cb + (size_t)c * 4096];
    }
    float pA = 1.f, sA = 0.f;
#pragma unroll
    for (int c = 0; c < 16; c++) { sA = fmaf(pv[c], sA, sv[c]); pA *= pv[c]; }
    gP[g2 * 32 + cl2] = pA;
    gS[g2 * 32 + cl2] = sA;
    __syncthreads();
    float h = 0.f;
    for (int gg = 0; gg < g2; gg++)
        h = fmaf(gP[gg * 32 + cl2], h, gS[gg * 32 + cl2]);
#pragma unroll
    for (int c = 0; c < 16; c++) {
        S_H0[cb + (size_t)c * 4096] = h;          // H0 for chunk (g2*16+c), in place
        h = fmaf(pv[c], h, sv[c]);
    }
}

// ===== kernel 3: re-scan + DFT(MFMA) + wc(MFMA) + g + inverse(MFMA) + epilogue =====
// Wave (wm=wave>>1, wx=wave&1) owns 2 timestep-rows x 32 x-cols per gulp.
// LDS map (bytes):
//   [0, 32768)      A-tile bf16 [64m][256d] swizzled; wc bf16 [16r][1024n] after gulps
//   [32768, 65536)  hf bf16 [16 r][64 x][16 i]
//   [65536, 67712)  g_s bf16 [16 r][68]
//   [67712, 68736)  cc_b bf16 [16 r][32 o']
//   [68736, 69760)  bc_s f32 [16 t][16 n]
__global__ __launch_bounds__(256, 2) void k_fused(
        const unsigned int* __restrict__ dxn,
        const float* __restrict__ xin, const float* __restrict__ D_param,
        const float* __restrict__ Bc, const float* __restrict__ Cc,
        const float* __restrict__ A_log, const float* __restrict__ H0,
        float* __restrict__ out,
        const __hip_bfloat16* __restrict__ E_t, const __hip_bfloat16* __restrict__ wfrag,
        const __hip_bfloat16* __restrict__ E_inv)
{
    __shared__ __align__(16) char smem[69760];
    __bf16* hfb  = (__bf16*)(smem + 32768);
    __bf16* gsb  = (__bf16*)(smem + 65536);
    __bf16* ccb  = (__bf16*)(smem + 67712);
    float*  bc_s = (float*)(smem + 68736);

    int tid = threadIdx.x, wave = tid >> 6, lane = tid & 63;
    int wm = wave >> 1, wx = wave & 1;
    int blk = blockIdx.x;
    int grow0 = blk * CL;
    int d = tid;

    // ---- setup ----
    bc_s[tid] = Bc[(size_t)grow0 * 16 + tid];
    {
        float ccv = Cc[(size_t)grow0 * 16 + tid];
        int r = tid >> 4, o = tid & 15;
        ccb[r * 32 + o] = (__bf16)ccv;
        ccb[r * 32 + 16 + o] = (__bf16)0.f;
    }
    unsigned int dxnv[16];
#pragma unroll
    for (int t = 0; t < 16; t++) dxnv[t] = dxn[(size_t)(grow0 + t) * D_ + d];
    float ar[16], h[16];
    {
        size_t ho = (size_t)blk * 4096 + d * 16;
#pragma unroll
        for (int q = 0; q < 4; q++) {
            f32x4 a4 = *(const f32x4*)&A_log[d * 16 + q * 4];
            f32x4 h4 = *(const f32x4*)&H0[ho + q * 4];
#pragma unroll
            for (int k = 0; k < 4; k++) { ar[q*4+k] = -__expf(a4[k]); h[q*4+k] = h4[k]; }
        }
    }
    bool uni = true;
#pragma unroll
    for (int n = 1; n < 16; n++) uni = uni && (ar[n] == ar[0]);
    float ar0 = ar[0];

    // ---- E fragments for this wave's 32 x-columns (VGPR-resident) ----
    bf16x8 bfragAll[2][8];
#pragma unroll
    for (int nt2 = 0; nt2 < 2; nt2++) {
        int xa = wx * 32 + nt2 * 16 + (lane & 15);
#pragma unroll
        for (int ks = 0; ks < 8; ks++)
            bfragAll[nt2][ks] = *(const bf16x8*)(E_t + xa * 256 + ks * 32 + ((lane >> 4) * 8));
    }
    int swz = (lane & 7) << 4;
    f32x4 acc[2][2];
#pragma unroll
    for (int a = 0; a < 2; a++)
#pragma unroll
        for (int b = 0; b < 2; b++) { acc[a][b][0]=0.f; acc[a][b][1]=0.f; acc[a][b][2]=0.f; acc[a][b][3]=0.f; }
    __syncthreads();

    // ---- 4 gulps: scan -> A-tile; DFT MFMA -> hf [r][x][i] ----
#pragma unroll
    for (int g = 0; g < 4; g++) {
        if (uni) {
#pragma unroll
            for (int tl = 0; tl < 4; tl++) {
                unsigned int v = dxnv[g * 4 + tl];
                float dl = __uint_as_float(v << 16);
                float dx = dl * __uint_as_float(v & 0xffff0000u);
                float e = __expf(dl * ar0);
#pragma unroll
                for (int n = 0; n < 16; n++) {
                    h[n] = fmaf(e, h[n], dx * bc_s[(g * 4 + tl) * 16 + n]);
                    int m = tl * 16 + n;
                    *(__bf16*)(smem + m * 512 + ((d * 2) ^ ((m & 7) << 4))) = (__bf16)h[n];
                }
            }
        } else {
#pragma unroll
            for (int tl = 0; tl < 4; tl++) {
                unsigned int v = dxnv[g * 4 + tl];
                float dl = __uint_as_float(v << 16);
                float dx = dl * __uint_as_float(v & 0xffff0000u);
#pragma unroll
                for (int n = 0; n < 16; n++) {
                    float e = __expf(dl * ar[n]);
                    h[n] = fmaf(e, h[n], dx * bc_s[(g * 4 + tl) * 16 + n]);
                    int m = tl * 16 + n;
                    *(__bf16*)(smem + m * 512 + ((d * 2) ^ ((m & 7) << 4))) = (__bf16)h[n];
                }
            }
        }
        __syncthreads();
        // DFT MFMA: wave computes rows (tl = wm*2 + tl2), x-cols wx*32..+31
#pragma unroll
        for (int ks = 0; ks < 8; ks++) {
#pragma unroll
            for (int tl2 = 0; tl2 < 2; tl2++) {
                int m = (wm * 2 + tl2) * 16 + (lane & 15);
                bf16x8 af = *(const bf16x8*)(smem + m * 512 + ((ks * 64 + ((lane >> 4) * 16)) ^ swz));
#pragma unroll
                for (int nt2 = 0; nt2 < 2; nt2++)
                    acc[tl2][nt2] = __builtin_amdgcn_mfma_f32_16x16x32_bf16(af, bfragAll[nt2][ks], acc[tl2][nt2], 0, 0, 0);
            }
        }
        // hf store (vectorized b64: 4 consecutive i) + acc reset
#pragma unroll
        for (int tl2 = 0; tl2 < 2; tl2++) {
            int r = g * 4 + wm * 2 + tl2;
#pragma unroll
            for (int nt2 = 0; nt2 < 2; nt2++) {
                int xcol = wx * 32 + nt2 * 16 + (lane & 15);
                bf16x4 pk;
#pragma unroll
                for (int k = 0; k < 4; k++) { pk[k] = (__bf16)acc[tl2][nt2][k]; acc[tl2][nt2][k] = 0.f; }
                *(bf16x4*)(&hfb[r * 1024 + xcol * 16 + (lane >> 4) * 4]) = pk;
            }
        }
        __syncthreads();
    }

    // ---- prefetch epilogue inputs (hide HBM latency under wc+g) ----
    float xpf[4][4], xnpf[4][4], dpf[4];
#pragma unroll
    for (int ntl = 0; ntl < 4; ntl++) {
        int dcol = (wave * 4 + ntl) * 16 + (lane & 15);
        dpf[ntl] = D_param[dcol];
#pragma unroll
        for (int q = 0; q < 4; q++) {
            int r = (lane >> 4) * 4 + q;
            size_t go = (size_t)(grow0 + r) * D_ + dcol;
            xpf[ntl][q] = xin[go];
            xnpf[ntl][q] = __uint_as_float(dxn[go] & 0xffff0000u);
        }
    }

    // ---- wc = Cc @ w via MFMA (M=16 r, K=32 o', N=1024), into dead A-tile region ----
    {
        bf16x8 ccf = *(const bf16x8*)((char*)ccb + (lane & 15) * 64 + ((lane >> 4) * 16));
#pragma unroll
        for (int ntl = 0; ntl < 16; ntl++) {
            int nt = wave * 16 + ntl;
            f32x4 a = {0.f, 0.f, 0.f, 0.f};
            bf16x8 wf = *(const bf16x8*)(wfrag + (nt * 64 + lane) * 8);
            a = __builtin_amdgcn_mfma_f32_16x16x32_bf16(ccf, wf, a, 0, 0, 0);
            int col = nt * 16 + (lane & 15);
#pragma unroll
            for (int q = 0; q < 4; q++) {
                int r = (lane >> 4) * 4 + q;
                *(__bf16*)(smem + r * 2048 + col * 2) = (__bf16)a[q];
            }
        }
    }
    __syncthreads();

    // ---- g[r,x] = sum_i hf[r,x,i] * wc[r,x,i] (complex); thread = (r, 2 x's) ----
    {
        __bf16* wcb = (__bf16*)smem;
        int r = tid >> 4, x2 = tid & 15;
#pragma unroll
        for (int xh = 0; xh < 2; xh++) {
            int xs = xh * 16 + x2;
            bf16x8 hra = *(const bf16x8*)(&hfb[r * 1024 + xs * 16]);
            bf16x8 hrb = *(const bf16x8*)(&hfb[r * 1024 + xs * 16 + 8]);
            bf16x8 hia = *(const bf16x8*)(&hfb[r * 1024 + (xs + 32) * 16]);
            bf16x8 hib = *(const bf16x8*)(&hfb[r * 1024 + (xs + 32) * 16 + 8]);
            bf16x8 wra = *(const bf16x8*)(&wcb[r * 1024 + xs * 16]);
            bf16x8 wrb = *(const bf16x8*)(&wcb[r * 1024 + xs * 16 + 8]);
            bf16x8 wia = *(const bf16x8*)(&wcb[r * 1024 + 512 + xs * 16]);
            bf16x8 wib = *(const bf16x8*)(&wcb[r * 1024 + 512 + xs * 16 + 8]);
            float gre = 0.f, gim = 0.f;
#pragma unroll
            for (int k = 0; k < 8; k++) {
                float hr = (float)hra[k], hi = (float)hia[k];
                float wr = (float)wra[k], wi = (float)wia[k];
                gre = fmaf(hr, wr, gre); gre = fmaf(-hi, wi, gre);
                gim = fmaf(hr, wi, gim); gim = fmaf(hi, wr, gim);
                float hr2 = (float)hrb[k], hi2 = (float)hib[k];
                float wr2 = (float)wrb[k], wi2 = (float)wib[k];
                gre = fmaf(hr2, wr2, gre); gre = fmaf(-hi2, wi2, gre);
                gim = fmaf(hr2, wi2, gim); gim = fmaf(hi2, wr2, gim);
            }
            float sc = xs ? 2.f : 1.f;
            gsb[r * 68 + xs]      = (__bf16)(gre * sc);
            gsb[r * 68 + 32 + xs] = (__bf16)(gim * sc);
        }
    }
    __syncthreads();

    // ---- inverse DFT via MFMA (M=16 r, K=64, N=256 d') + epilogue ----
    {
        bf16x8 ga0 = *(const bf16x8*)((char*)gsb + (lane & 15) * 136 + ((lane >> 4) * 16));
        bf16x8 ga1 = *(const bf16x8*)((char*)gsb + (lane & 15) * 136 + 64 + ((lane >> 4) * 16));
#pragma unroll
        for (int ntl = 0; ntl < 4; ntl++) {
            int nt = wave * 4 + ntl;
            f32x4 a = {0.f, 0.f, 0.f, 0.f};
            a = __builtin_amdgcn_mfma_f32_16x16x32_bf16(
                    ga0, *(const bf16x8*)(E_inv + ((nt * 2 + 0) * 64 + lane) * 8), a, 0, 0, 0);
            a = __builtin_amdgcn_mfma_f32_16x16x32_bf16(
                    ga1, *(const bf16x8*)(E_inv + ((nt * 2 + 1) * 64 + lane) * 8), a, 0, 0, 0);
            int dcol = nt * 16 + (lane & 15);
#pragma unroll
            for (int q = 0; q < 4; q++) {
                int r = (lane >> 4) * 4 + q;
                size_t go = (size_t)(grow0 + r) * D_ + dcol;
                out[go] = xpf[ntl][q] + dpf[ntl] * xnpf[ntl][q] + a[q] * (1.f / 256.f);
            }
        }
    }
}

// ===== launch =====
extern "C" void kernel_launch(void* const* d_in, const int* in_sizes, int n_in,
                              void* d_out, int out_size, void* d_ws, size_t ws_size,
                              hipStream_t stream)
{
    const float* x       = (const float*)d_in[0];
    const float* ln_g    = (const float*)d_in[1];
    const float* ln_b    = (const float*)d_in[2];
    const float* W_xproj = (const float*)d_in[3];
    const float* W_dt    = (const float*)d_in[4];
    const float* b_dt    = (const float*)d_in[5];
    const float* A_log   = (const float*)d_in[6];
    const float* D_param = (const float*)d_in[7];
    const float* w_re    = (const float*)d_in[8];
    const float* w_im    = (const float*)d_in[9];

    float* ws    = (float*)d_ws;
    float* S_H0  = ws;                               // 2M floats (S, then H0 in place)
    unsigned int* dxn = (unsigned int*)(S_H0 + 2097152); // 2M u32 (bf16 dlt | bf16 xn)
    float* Bc    = (float*)(dxn + 2097152);          // 131072
    float* Cc    = Bc + 131072;                      // 131072
    float* dsum  = Cc + 131072;                      // 131072
    __hip_bfloat16* tab = (__hip_bfloat16*)(dsum + 131072);
    __hip_bfloat16* E_t   = tab;                     // 16384 bf16
    __hip_bfloat16* Wfrag = tab + 16384;             // 16384
    __hip_bfloat16* wfrag = tab + 32768;             // 32768
    __hip_bfloat16* E_inv = tab + 65536;             // 16384
    float* out = (float*)d_out;

    hipLaunchKernelGGL(k_prep, dim3(320), dim3(256), 0, stream,
                       W_xproj, w_re, w_im, E_t, Wfrag, wfrag, E_inv);
    hipLaunchKernelGGL(k_lnscan, dim3(B_*NC), dim3(256), 0, stream,
                       x, ln_g, ln_b, W_dt, b_dt, A_log, Wfrag,
                       dxn, Bc, Cc, dsum, S_H0);
    hipLaunchKernelGGL(k_scan_par, dim3(B_*NC), dim3(256), 0, stream, A_log, dsum, S_H0);
    hipLaunchKernelGGL(k_fused, dim3(B_*NC), dim3(256), 0, stream,
                       dxn, x, D_param, Bc, Cc, A_log, S_H0, out, E_t, wfrag, E_inv);
}